// Round 2
// baseline (11814.965 us; speedup 1.0000x reference)
//
#include <hip/hip_runtime.h>
#include <cmath>

#define NB   32
#define TE   128
#define TD   32
#define VOC  32000
#define EMB  256
#define HH   512
#define CTXD 1024

// ws layout (float offsets)
#define OU   1024                         // ucat [2][129][NB][768]
#define OEO  (OU  + 2*129*NB*768)         // enc_out [NB][TE][CTXD]
#define OEP  (OEO + NB*TE*CTXD)           // epre [NB][TE][8]
#define OHD  (OEP + NB*TE*8)              // hdec [TD+1][NB][HH]
#define OCX  (OHD + (TD+1)*NB*HH)         // ctx  [TD][NB][CTXD]
#define WSEND (OCX + TD*NB*CTXD)          // 12,157,952 floats ~48.6MB

__device__ __forceinline__ float sigf(float x) { return 1.0f / (1.0f + expf(-x)); }

__device__ __forceinline__ void stg1(float* p, float v) {
  __hip_atomic_store(p, v, __ATOMIC_RELAXED, __HIP_MEMORY_SCOPE_AGENT);
}

// two-level grid barrier: 16 groups x 16 blocks, last-arriver promotes.
// root cnt at bar[0], root gen at bar[8]; group g: cnt bar[32+g*32], gen +8.
__device__ __forceinline__ void gbar2(int* bar) {
  __syncthreads();
  if (threadIdx.x == 0) {
    const int bid = blockIdx.x;
    int* gcnt = bar + 32 + (bid >> 4) * 32;
    int* ggen = gcnt + 8;
    int g = __hip_atomic_load(ggen, __ATOMIC_RELAXED, __HIP_MEMORY_SCOPE_AGENT);
    int v = __hip_atomic_fetch_add(gcnt, 1, __ATOMIC_ACQ_REL, __HIP_MEMORY_SCOPE_AGENT);
    if (v == 15) {
      int* rcnt = bar;
      int* rgen = bar + 8;
      int rg = __hip_atomic_load(rgen, __ATOMIC_RELAXED, __HIP_MEMORY_SCOPE_AGENT);
      int rv = __hip_atomic_fetch_add(rcnt, 1, __ATOMIC_ACQ_REL, __HIP_MEMORY_SCOPE_AGENT);
      if (rv == 15) {
        __hip_atomic_store(rcnt, 0, __ATOMIC_RELAXED, __HIP_MEMORY_SCOPE_AGENT);
        __hip_atomic_fetch_add(rgen, 1, __ATOMIC_RELEASE, __HIP_MEMORY_SCOPE_AGENT);
      } else {
        int it = 0;
        while (__hip_atomic_load(rgen, __ATOMIC_ACQUIRE, __HIP_MEMORY_SCOPE_AGENT) == rg) {
          __builtin_amdgcn_s_sleep(1);
          if (++it > (1 << 22)) break;  // safety bail: garbage beats hang
        }
      }
      __hip_atomic_store(gcnt, 0, __ATOMIC_RELAXED, __HIP_MEMORY_SCOPE_AGENT);
      __hip_atomic_fetch_add(ggen, 1, __ATOMIC_RELEASE, __HIP_MEMORY_SCOPE_AGENT);
    } else {
      int it = 0;
      while (__hip_atomic_load(ggen, __ATOMIC_ACQUIRE, __HIP_MEMORY_SCOPE_AGENT) == g) {
        __builtin_amdgcn_s_sleep(1);
        if (++it > (1 << 22)) break;
      }
    }
  }
  __syncthreads();
}

// ---------------- BiLSTM scan: 256 blocks x 512 thr, persistent ----------------
// block: dir = bid>>7, ob = bid&127 -> h-columns j0..j0+3 (all 4 gates), 16 W rows
// thread: kq = tid>>5 (k-chunk of 48), jj = (tid>>3)&3 (column), bg = tid&7 (4 batches)
// thread tile: 4 gates x 4 batches, K=48 -> 768 FMA per 96 b128 loads
__global__ void __launch_bounds__(512)
scan_kernel(const int* __restrict__ enc_in, const int* __restrict__ lens,
            const float* __restrict__ emb_src,
            const float* __restrict__ Wih_f, const float* __restrict__ Whh_f,
            const float* __restrict__ bih_f, const float* __restrict__ bhh_f,
            const float* __restrict__ Wih_b, const float* __restrict__ Whh_b,
            const float* __restrict__ bih_b, const float* __restrict__ bhh_b,
            float* __restrict__ ws)
{
  int* bar = (int*)ws;
  float* ucat = ws + OU;
  float* eo   = ws + OEO;

  const int tid = threadIdx.x;
  const int bid = blockIdx.x;

  asm volatile("buffer_inv sc1" ::: "memory");  // purge stale clean lines (graph replays)

  // ---- pre-phase: fill x region of ucat for both dirs, zero h[0] ----
  {
    const int gt = bid * 512 + tid;
    for (int i4 = gt; i4 < 2 * TE * NB * 64; i4 += 131072) {
      int k4 = i4 & 63;
      int b  = (i4 >> 6) & 31;
      int s  = (i4 >> 11) & 127;
      int d  = i4 >> 18;
      int t  = s;
      if (d) { int L = lens[b]; t = (s < L) ? (L - 1 - s) : s; }
      int tok = enc_in[b * TE + t];
      float4 v = *(const float4*)&emb_src[(size_t)tok * EMB + k4 * 4];
      float* dst = &ucat[(((size_t)d * 129 + s) * NB + b) * 768 + k4 * 4];
      stg1(dst + 0, v.x); stg1(dst + 1, v.y); stg1(dst + 2, v.z); stg1(dst + 3, v.w);
    }
    if (gt < 2 * NB * HH) {
      int j = gt & 511, b = (gt >> 9) & 31, d = gt >> 14;
      stg1(&ucat[(((size_t)d * 129) * NB + b) * 768 + 256 + j], 0.0f);
    }
  }
  gbar2(bar);

  const int dir = bid >> 7;
  const int ob  = bid & 127;
  const int j0  = ob * 4;
  const int kq  = tid >> 5;
  const int jj  = (tid >> 3) & 3;
  const int bg  = tid & 7;

  const float* Wih = dir ? Wih_b : Wih_f;
  const float* Whh = dir ? Whh_b : Whh_f;

  // per-gate weight row pointers at this thread's k-chunk
  const float* pWi[4];
  const float* pWh[4];
  #pragma unroll
  for (int g = 0; g < 4; ++g) {
    int o = g * HH + j0 + jj;
    pWi[g] = Wih + (size_t)o * EMB + kq * 48;
    pWh[g] = Whh + (size_t)o * HH + kq * 48 - 256;   // valid only when col>=256
  }

  __shared__ float red2[128 * 32];   // [kqh*16 + g*4 + jj][batch]

  // updater role (tid < 128): one (column jj_u, batch b_u)
  const int b_u  = tid & 31;
  const int jj_u = tid >> 5;
  const int j_u  = j0 + jj_u;
  const int Lu   = lens[b_u];
  float bs[4] = {0.f, 0.f, 0.f, 0.f};
  if (tid < 128) {
    const float* bih = dir ? bih_b : bih_f;
    const float* bhh = dir ? bhh_b : bhh_f;
    #pragma unroll
    for (int g = 0; g < 4; ++g) bs[g] = bih[g * HH + j_u] + bhh[g * HH + j_u];
  }
  float cst = 0.0f;

  for (int s = 0; s < TE; ++s) {
    const float* ubase = ucat + (((size_t)dir * 129 + s) * NB) * 768 + kq * 48;
    float4 ua[4];
    #pragma unroll
    for (int bb = 0; bb < 4; ++bb)
      ua[bb] = *(const float4*)&ubase[(bg * 4 + bb) * 768];
    float acc[4][4] = {};

    #pragma unroll
    for (int k4 = 0; k4 < 12; ++k4) {
      float4 un[4];
      #pragma unroll
      for (int bb = 0; bb < 4; ++bb)
        un[bb] = (k4 < 11) ? *(const float4*)&ubase[(bg * 4 + bb) * 768 + (k4 + 1) * 4]
                           : ua[bb];
      const bool usex = (kq * 48 + k4 * 4) < 256;
      #pragma unroll
      for (int g = 0; g < 4; ++g) {
        const float* wp = usex ? pWi[g] : pWh[g];
        float4 wv = *(const float4*)&wp[k4 * 4];
        #pragma unroll
        for (int bb = 0; bb < 4; ++bb) {
          acc[g][bb] = fmaf(wv.x, ua[bb].x, acc[g][bb]);
          acc[g][bb] = fmaf(wv.y, ua[bb].y, acc[g][bb]);
          acc[g][bb] = fmaf(wv.z, ua[bb].z, acc[g][bb]);
          acc[g][bb] = fmaf(wv.w, ua[bb].w, acc[g][bb]);
        }
      }
      #pragma unroll
      for (int bb = 0; bb < 4; ++bb) ua[bb] = un[bb];
    }

    // pair-reduce kq (even,odd) in-wave, then stage to LDS
    float v[16];
    #pragma unroll
    for (int g = 0; g < 4; ++g)
      #pragma unroll
      for (int bb = 0; bb < 4; ++bb)
        v[g * 4 + bb] = acc[g][bb] + __shfl_xor(acc[g][bb], 32, 64);
    if ((tid & 32) == 0) {
      #pragma unroll
      for (int g = 0; g < 4; ++g)
        #pragma unroll
        for (int bb = 0; bb < 4; ++bb)
          red2[((kq >> 1) * 16 + g * 4 + jj) * 32 + bg * 4 + bb] = v[g * 4 + bb];
    }
    __syncthreads();

    if (tid < 128) {
      float gv[4];
      #pragma unroll
      for (int g = 0; g < 4; ++g) {
        float x = 0.0f;
        #pragma unroll
        for (int kh = 0; kh < 8; ++kh)
          x += red2[(kh * 16 + g * 4 + jj_u) * 32 + b_u];
        gv[g] = x + bs[g];
      }
      float c = sigf(gv[1]) * cst + sigf(gv[0]) * tanhf(gv[2]);
      cst = c;
      float h = sigf(gv[3]) * tanhf(c);
      stg1(&ucat[(((size_t)dir * 129 + s + 1) * NB + b_u) * 768 + 256 + j_u], h);
      if (dir == 0) {
        eo[((size_t)b_u * TE + s) * CTXD + j_u] = (s < Lu) ? h : 0.0f;
      } else {
        int pos = (s < Lu) ? (Lu - 1 - s) : s;
        eo[((size_t)b_u * TE + pos) * CTXD + HH + j_u] = (s < Lu) ? h : 0.0f;
      }
    }
    gbar2(bar);
  }
}

// ---------------- Decoder: 256 blocks x 512 thr, persistent ----------------
__global__ void __launch_bounds__(512)
dec_kernel(const int* __restrict__ dec_in, const int* __restrict__ lens,
           const float* __restrict__ emb_tgt,
           const float* __restrict__ gWih, const float* __restrict__ gWhh,
           const float* __restrict__ gbih, const float* __restrict__ gbhh,
           const float* __restrict__ attn_W, const float* __restrict__ attn_b,
           const float* __restrict__ attn_v,
           float* __restrict__ ws)
{
  int* bar = (int*)ws;
  float* eo = ws + OEO;
  float* ep = ws + OEP;
  float* hd = ws + OHD;
  float* cx = ws + OCX;

  const int tid = threadIdx.x;
  const int bid = blockIdx.x;

  asm volatile("buffer_inv sc1" ::: "memory");

  // pre-phase: epre[b][t][a] = enc_out@attn_W[:1024] + attn_b ; hdec[0]=0
  {
    const int gt = bid * 512 + tid;
    if (gt < NB * TE * 8) {
      int a = gt & 7;
      int t = (gt >> 3) & 127;
      int b = gt >> 10;
      float acc = attn_b[a];
      const float* er = &eo[((size_t)b * TE + t) * CTXD];
      for (int d = 0; d < CTXD; d += 4) {
        float4 ev = *(const float4*)&er[d];
        acc = fmaf(ev.x, attn_W[(d + 0) * 8 + a], acc);
        acc = fmaf(ev.y, attn_W[(d + 1) * 8 + a], acc);
        acc = fmaf(ev.z, attn_W[(d + 2) * 8 + a], acc);
        acc = fmaf(ev.w, attn_W[(d + 3) * 8 + a], acc);
      }
      stg1(&ep[gt], acc);
    }
    if (gt < NB * HH) stg1(&hd[gt], 0.0f);
  }
  gbar2(bar);

  __shared__ float hpp[64];
  __shared__ float hpv[8];
  __shared__ float elds[128];
  __shared__ float wlds[128];
  __shared__ float red[64];
  __shared__ float gi2[2][2][3][32];
  __shared__ float gh2[2][2][3][32];

  const int pb = bid >> 3;   // P2 batch
  const int ds = bid & 7;    // P2 ctx d-slice
  const int Lb = lens[pb];

  for (int s = 0; s < TD; ++s) {
    // ---- P2: attention scores, softmax, ctx ----
    {
      const float* hrow = &hd[(size_t)s * NB * HH + pb * HH];
      if (tid < 64) {
        int a = tid >> 3, p = tid & 7;
        float acc = 0.0f;
        const float* wp = &attn_W[(CTXD + p * 64) * 8 + a];
        const float* h8 = &hrow[p * 64];
        for (int q = 0; q < 64; ++q) acc = fmaf(h8[q], wp[q * 8], acc);
        hpp[tid] = acc;
      }
      __syncthreads();
      if (tid < 8) {
        float x = 0.0f;
        for (int p = 0; p < 8; ++p) x += hpp[tid * 8 + p];
        hpv[tid] = x;
      }
      __syncthreads();
      if (tid < 128) {
        float evv;
        if (tid < Lb) {
          evv = 0.0f;
          const float* e8 = &ep[((size_t)pb * TE + tid) * 8];
          #pragma unroll
          for (int a = 0; a < 8; ++a) evv += tanhf(e8[a] + hpv[a]) * attn_v[a];
        } else evv = -1e9f;
        elds[tid] = evv;
      }
      __syncthreads();
      if (tid < 64) red[tid] = fmaxf(elds[tid], elds[tid + 64]);
      __syncthreads();
      for (int w = 32; w > 0; w >>= 1) {
        if (tid < w) red[tid] = fmaxf(red[tid], red[tid + w]);
        __syncthreads();
      }
      float mx = red[0];
      __syncthreads();
      if (tid < 128) wlds[tid] = expf(elds[tid] - mx);
      __syncthreads();
      if (tid < 64) red[tid] = wlds[tid] + wlds[tid + 64];
      __syncthreads();
      for (int w = 32; w > 0; w >>= 1) {
        if (tid < w) red[tid] += red[tid + w];
        __syncthreads();
      }
      float inv = 1.0f / red[0];
      __syncthreads();
      if (tid < 128) {
        int d = ds * 128 + tid;
        float acc = 0.0f;
        const float* ebase = &eo[((size_t)pb * TE) * CTXD + d];
        for (int t = 0; t < TE; ++t)
          acc = fmaf(wlds[t], ebase[(size_t)t * CTXD], acc);
        stg1(&cx[((size_t)s * NB + pb) * CTXD + d], acc * inv);
      }
    }
    gbar2(bar);
    // ---- P3: GRU cell -> hdec[s+1] ----
    {
      if (tid < 384) {
        int b  = tid & 31;
        int q  = tid >> 5;
        int g  = q % 3;
        int jl = (q / 3) & 1;
        int kh = q / 6;
        int j  = bid * 2 + jl;
        int row = g * HH + j;
        int tok = dec_in[b * TD + s];
        const float* wi  = &gWih[(size_t)row * (EMB + CTXD)];
        const float* wh  = &gWhh[(size_t)row * HH];
        const float* cxr = &cx[((size_t)s * NB + b) * CTXD];
        const float* hr  = &hd[(size_t)s * NB * HH + b * HH];
        float ai = 0.0f, ah = 0.0f;
        if (kh == 0) {
          const float* em = &emb_tgt[(size_t)tok * EMB];
          for (int k = 0; k < 256; k += 4) {
            float4 xv = *(const float4*)&em[k];
            float4 wv = *(const float4*)&wi[k];
            ai = fmaf(xv.x, wv.x, ai); ai = fmaf(xv.y, wv.y, ai);
            ai = fmaf(xv.z, wv.z, ai); ai = fmaf(xv.w, wv.w, ai);
          }
          for (int k = 256; k < 640; k += 4) {
            float4 xv = *(const float4*)&cxr[k - 256];
            float4 wv = *(const float4*)&wi[k];
            ai = fmaf(xv.x, wv.x, ai); ai = fmaf(xv.y, wv.y, ai);
            ai = fmaf(xv.z, wv.z, ai); ai = fmaf(xv.w, wv.w, ai);
          }
          for (int k = 0; k < 256; k += 4) {
            float4 hv = *(const float4*)&hr[k];
            float4 wv = *(const float4*)&wh[k];
            ah = fmaf(hv.x, wv.x, ah); ah = fmaf(hv.y, wv.y, ah);
            ah = fmaf(hv.z, wv.z, ah); ah = fmaf(hv.w, wv.w, ah);
          }
        } else {
          for (int k = 640; k < 1280; k += 4) {
            float4 xv = *(const float4*)&cxr[k - 256];
            float4 wv = *(const float4*)&wi[k];
            ai = fmaf(xv.x, wv.x, ai); ai = fmaf(xv.y, wv.y, ai);
            ai = fmaf(xv.z, wv.z, ai); ai = fmaf(xv.w, wv.w, ai);
          }
          for (int k = 256; k < 512; k += 4) {
            float4 hv = *(const float4*)&hr[k];
            float4 wv = *(const float4*)&wh[k];
            ah = fmaf(hv.x, wv.x, ah); ah = fmaf(hv.y, wv.y, ah);
            ah = fmaf(hv.z, wv.z, ah); ah = fmaf(hv.w, wv.w, ah);
          }
        }
        gi2[kh][jl][g][b] = ai;
        gh2[kh][jl][g][b] = ah;
      }
      __syncthreads();
      if (tid < 64) {
        int b = tid & 31, jl = tid >> 5;
        int j = bid * 2 + jl;
        float giR = gi2[0][jl][0][b] + gi2[1][jl][0][b] + gbih[j];
        float ghR = gh2[0][jl][0][b] + gh2[1][jl][0][b] + gbhh[j];
        float giZ = gi2[0][jl][1][b] + gi2[1][jl][1][b] + gbih[HH + j];
        float ghZ = gh2[0][jl][1][b] + gh2[1][jl][1][b] + gbhh[HH + j];
        float giN = gi2[0][jl][2][b] + gi2[1][jl][2][b] + gbih[2 * HH + j];
        float ghN = gh2[0][jl][2][b] + gh2[1][jl][2][b] + gbhh[2 * HH + j];
        float r = sigf(giR + ghR);
        float z = sigf(giZ + ghZ);
        float n = tanhf(giN + r * ghN);
        float hold = hd[(size_t)s * NB * HH + b * HH + j];
        float hnew = (1.0f - z) * n + z * hold;
        stg1(&hd[(size_t)(s + 1) * NB * HH + b * HH + j], hnew);
      }
    }
    gbar2(bar);
  }
}

// ---------------- Classifier: [1024,512] @ clf_W^T [512,32000], relu ----------------
__global__ void __launch_bounds__(256)
clf_kernel(const float* __restrict__ hdec, const float* __restrict__ W,
           const float* __restrict__ bias, float* __restrict__ out)
{
  __shared__ __align__(16) float As[16][68];
  __shared__ __align__(16) float Bs[16][68];
  const int tid = threadIdx.x;
  const int tx = tid & 15, ty = tid >> 4;
  const int n0 = blockIdx.x * 64, m0 = blockIdx.y * 64;
  float acc[4][4] = {};
  const int lr = tid >> 2;
  const int lk = (tid & 3) * 4;
  const int r  = m0 + lr;                       // r = b*TD + t
  const float* arow = hdec + (((size_t)(r & 31) + 1) * NB + (r >> 5)) * HH;
  const float* brow = W + (size_t)(n0 + lr) * HH;

  for (int kc = 0; kc < HH; kc += 16) {
    float4 av = *(const float4*)&arow[kc + lk];
    float4 bv = *(const float4*)&brow[kc + lk];
    __syncthreads();
    As[lk + 0][lr] = av.x; As[lk + 1][lr] = av.y;
    As[lk + 2][lr] = av.z; As[lk + 3][lr] = av.w;
    Bs[lk + 0][lr] = bv.x; Bs[lk + 1][lr] = bv.y;
    Bs[lk + 2][lr] = bv.z; Bs[lk + 3][lr] = bv.w;
    __syncthreads();
    #pragma unroll
    for (int kk = 0; kk < 16; ++kk) {
      float4 a4 = *(const float4*)&As[kk][ty * 4];
      float4 b4 = *(const float4*)&Bs[kk][tx * 4];
      acc[0][0] = fmaf(a4.x, b4.x, acc[0][0]); acc[0][1] = fmaf(a4.x, b4.y, acc[0][1]);
      acc[0][2] = fmaf(a4.x, b4.z, acc[0][2]); acc[0][3] = fmaf(a4.x, b4.w, acc[0][3]);
      acc[1][0] = fmaf(a4.y, b4.x, acc[1][0]); acc[1][1] = fmaf(a4.y, b4.y, acc[1][1]);
      acc[1][2] = fmaf(a4.y, b4.z, acc[1][2]); acc[1][3] = fmaf(a4.y, b4.w, acc[1][3]);
      acc[2][0] = fmaf(a4.z, b4.x, acc[2][0]); acc[2][1] = fmaf(a4.z, b4.y, acc[2][1]);
      acc[2][2] = fmaf(a4.z, b4.z, acc[2][2]); acc[2][3] = fmaf(a4.z, b4.w, acc[2][3]);
      acc[3][0] = fmaf(a4.w, b4.x, acc[3][0]); acc[3][1] = fmaf(a4.w, b4.y, acc[3][1]);
      acc[3][2] = fmaf(a4.w, b4.z, acc[3][2]); acc[3][3] = fmaf(a4.w, b4.w, acc[3][3]);
    }
  }
  const int col = n0 + tx * 4;
  float4 bb4 = *(const float4*)&bias[col];
  #pragma unroll
  for (int i = 0; i < 4; ++i) {
    int row = m0 + ty * 4 + i;
    float4 o;
    o.x = fmaxf(acc[i][0] + bb4.x, 0.0f);
    o.y = fmaxf(acc[i][1] + bb4.y, 0.0f);
    o.z = fmaxf(acc[i][2] + bb4.z, 0.0f);
    o.w = fmaxf(acc[i][3] + bb4.w, 0.0f);
    *(float4*)&out[(size_t)row * VOC + col] = o;
  }
}

extern "C" void kernel_launch(void* const* d_in, const int* in_sizes, int n_in,
                              void* d_out, int out_size, void* d_ws, size_t ws_size,
                              hipStream_t stream)
{
  if (ws_size < (size_t)WSEND * 4) return;  // visible-failure guard

  const int* enc_in  = (const int*)d_in[0];
  const int* enc_len = (const int*)d_in[1];
  const int* dec_in  = (const int*)d_in[2];
  const float* emb_src = (const float*)d_in[4];
  const float* emb_tgt = (const float*)d_in[5];
  const float* Wih_f = (const float*)d_in[6];
  const float* Whh_f = (const float*)d_in[7];
  const float* bih_f = (const float*)d_in[8];
  const float* bhh_f = (const float*)d_in[9];
  const float* Wih_b = (const float*)d_in[10];
  const float* Whh_b = (const float*)d_in[11];
  const float* bih_b = (const float*)d_in[12];
  const float* bhh_b = (const float*)d_in[13];
  const float* gWih  = (const float*)d_in[14];
  const float* gWhh  = (const float*)d_in[15];
  const float* gbih  = (const float*)d_in[16];
  const float* gbhh  = (const float*)d_in[17];
  const float* attn_W = (const float*)d_in[18];
  const float* attn_b = (const float*)d_in[19];
  const float* attn_v = (const float*)d_in[20];
  const float* clf_W = (const float*)d_in[21];
  const float* clf_b = (const float*)d_in[22];
  float* ws  = (float*)d_ws;
  float* out = (float*)d_out;

  hipMemsetAsync(d_ws, 0, 4096, stream);  // barrier state
  scan_kernel<<<256, 512, 0, stream>>>(enc_in, enc_len, emb_src,
      Wih_f, Whh_f, bih_f, bhh_f, Wih_b, Whh_b, bih_b, bhh_b, ws);
  dec_kernel<<<256, 512, 0, stream>>>(dec_in, enc_len, emb_tgt,
      gWih, gWhh, gbih, gbhh, attn_W, attn_b, attn_v, ws);
  dim3 cg(VOC / 64, (NB * TD) / 64);
  clf_kernel<<<cg, 256, 0, stream>>>(ws + OHD, clf_W, clf_b, out);
}

// Round 3
// 9996.110 us; speedup vs baseline: 1.1820x; 1.1820x over previous
//
#include <hip/hip_runtime.h>
#include <cmath>

#define NB   32
#define TE   128
#define TD   32
#define VOC  32000
#define EMB  256
#define HH   512
#define CTXD 1024

// ws layout (float offsets). bar region: 2 dirs x 1024 ints.
#define OU   4096                         // ucat [2][129][NB][768]
#define OEO  (OU  + 2*129*NB*768)         // enc_out [NB][TE][CTXD]
#define OEP  (OEO + NB*TE*CTXD)           // epre [NB][TE][8]
#define OHD  (OEP + NB*TE*8)              // hdec [TD+1][NB][HH]
#define OCX  (OHD + (TD+1)*NB*HH)         // ctx  [TD][NB][CTXD]
#define WSEND (OCX + TD*NB*CTXD)          // ~48.6MB

__device__ __forceinline__ float sigf(float x) { return 1.0f / (1.0f + expf(-x)); }

__device__ __forceinline__ void stg1(float* p, float v) {
  __hip_atomic_store(p, v, __ATOMIC_RELAXED, __HIP_MEMORY_SCOPE_AGENT);
}

// Two-level grid barrier, ALL-RELAXED (no acquire: agent-scope acquire emits
// buffer_inv sc1 and nukes L2 every poll — R2's 1.8x regression).
// Correctness: __syncthreads drains vmcnt (sc1 data stores reached L3) before
// arrival RMW; readers touch per-step-fresh addresses only.
// Layout per region: root cnt bar[0], root gen bar[16]; group g: cnt bar[64+g*32], gen +16.
template<int NG, int GS>
__device__ __forceinline__ void gbarT(int* bar, int idx) {
  __syncthreads();
  if (threadIdx.x == 0) {
    int* gcnt = bar + 64 + (idx / GS) * 32;
    int* ggen = gcnt + 16;
    int g = __hip_atomic_load(ggen, __ATOMIC_RELAXED, __HIP_MEMORY_SCOPE_AGENT);
    int v = __hip_atomic_fetch_add(gcnt, 1, __ATOMIC_RELAXED, __HIP_MEMORY_SCOPE_AGENT);
    if (v == GS - 1) {
      int* rcnt = bar;
      int* rgen = bar + 16;
      int rg = __hip_atomic_load(rgen, __ATOMIC_RELAXED, __HIP_MEMORY_SCOPE_AGENT);
      int rv = __hip_atomic_fetch_add(rcnt, 1, __ATOMIC_RELAXED, __HIP_MEMORY_SCOPE_AGENT);
      if (rv == NG - 1) {
        __hip_atomic_store(rcnt, 0, __ATOMIC_RELAXED, __HIP_MEMORY_SCOPE_AGENT);
        asm volatile("s_waitcnt vmcnt(0)" ::: "memory");   // reset lands before gen bump
        __hip_atomic_fetch_add(rgen, 1, __ATOMIC_RELAXED, __HIP_MEMORY_SCOPE_AGENT);
      } else {
        int it = 0;
        while (__hip_atomic_load(rgen, __ATOMIC_RELAXED, __HIP_MEMORY_SCOPE_AGENT) == rg) {
          __builtin_amdgcn_s_sleep(1);
          if (++it > (1 << 22)) break;  // safety bail: garbage beats hang
        }
      }
      __hip_atomic_store(gcnt, 0, __ATOMIC_RELAXED, __HIP_MEMORY_SCOPE_AGENT);
      asm volatile("s_waitcnt vmcnt(0)" ::: "memory");
      __hip_atomic_fetch_add(ggen, 1, __ATOMIC_RELAXED, __HIP_MEMORY_SCOPE_AGENT);
    } else {
      int it = 0;
      while (__hip_atomic_load(ggen, __ATOMIC_RELAXED, __HIP_MEMORY_SCOPE_AGENT) == g) {
        __builtin_amdgcn_s_sleep(1);
        if (++it > (1 << 22)) break;
      }
    }
  }
  __syncthreads();
}

// ---------------- BiLSTM scan: 256 blocks x 512 thr, persistent ----------------
// Two independent 128-block halves (dir 0/1), each with its own barrier region.
// thread: kq = tid>>5 (k-chunk of 48), jj = (tid>>3)&3 (column), bg = tid&7 (4 batches)
__global__ void __launch_bounds__(512)
scan_kernel(const int* __restrict__ enc_in, const int* __restrict__ lens,
            const float* __restrict__ emb_src,
            const float* __restrict__ Wih_f, const float* __restrict__ Whh_f,
            const float* __restrict__ bih_f, const float* __restrict__ bhh_f,
            const float* __restrict__ Wih_b, const float* __restrict__ Whh_b,
            const float* __restrict__ bih_b, const float* __restrict__ bhh_b,
            float* __restrict__ ws)
{
  const int tid = threadIdx.x;
  const int bid = blockIdx.x;
  const int dir = bid >> 7;
  const int ob  = bid & 127;

  int* bar = (int*)ws + dir * 1024;
  float* ucat = ws + OU;
  float* eo   = ws + OEO;

  asm volatile("buffer_inv sc1" ::: "memory");  // purge stale clean lines (graph replays)

  // ---- pre-phase (per dir): fill x region of ucat, zero h[0] ----
  {
    const int gt = ob * 512 + tid;                 // 0..65535
    for (int i4 = gt; i4 < TE * NB * 64; i4 += 65536) {
      int k4 = i4 & 63;
      int b  = (i4 >> 6) & 31;
      int s  = i4 >> 11;
      int t  = s;
      if (dir) { int L = lens[b]; t = (s < L) ? (L - 1 - s) : s; }
      int tok = enc_in[b * TE + t];
      float4 v = *(const float4*)&emb_src[(size_t)tok * EMB + k4 * 4];
      float* dst = &ucat[(((size_t)dir * 129 + s) * NB + b) * 768 + k4 * 4];
      stg1(dst + 0, v.x); stg1(dst + 1, v.y); stg1(dst + 2, v.z); stg1(dst + 3, v.w);
    }
    if (gt < NB * HH) {
      int j = gt & 511, b = gt >> 9;
      stg1(&ucat[(((size_t)dir * 129) * NB + b) * 768 + 256 + j], 0.0f);
    }
  }
  gbarT<16, 8>(bar, ob);

  const int j0  = ob * 4;
  const int kq  = tid >> 5;
  const int jj  = (tid >> 3) & 3;
  const int bg  = tid & 7;

  const float* Wih = dir ? Wih_b : Wih_f;
  const float* Whh = dir ? Whh_b : Whh_f;

  const float* pWi[4];
  const float* pWh[4];
  #pragma unroll
  for (int g = 0; g < 4; ++g) {
    int o = g * HH + j0 + jj;
    pWi[g] = Wih + (size_t)o * EMB + kq * 48;
    pWh[g] = Whh + (size_t)o * HH + kq * 48 - 256;   // valid only when col>=256
  }

  __shared__ float red2[128 * 32];   // [kqh*16 + g*4 + jj][batch]

  const int b_u  = tid & 31;
  const int jj_u = tid >> 5;
  const int j_u  = j0 + jj_u;
  const int Lu   = lens[b_u];
  float bs[4] = {0.f, 0.f, 0.f, 0.f};
  if (tid < 128) {
    const float* bih = dir ? bih_b : bih_f;
    const float* bhh = dir ? bhh_b : bhh_f;
    #pragma unroll
    for (int g = 0; g < 4; ++g) bs[g] = bih[g * HH + j_u] + bhh[g * HH + j_u];
  }
  float cst = 0.0f;

  for (int s = 0; s < TE; ++s) {
    const float* ubase = ucat + (((size_t)dir * 129 + s) * NB) * 768 + kq * 48;
    float4 ua[4];
    #pragma unroll
    for (int bb = 0; bb < 4; ++bb)
      ua[bb] = *(const float4*)&ubase[(bg * 4 + bb) * 768];
    float acc[4][4] = {};

    #pragma unroll
    for (int k4 = 0; k4 < 12; ++k4) {
      float4 un[4];
      #pragma unroll
      for (int bb = 0; bb < 4; ++bb)
        un[bb] = (k4 < 11) ? *(const float4*)&ubase[(bg * 4 + bb) * 768 + (k4 + 1) * 4]
                           : ua[bb];
      const bool usex = (kq * 48 + k4 * 4) < 256;
      #pragma unroll
      for (int g = 0; g < 4; ++g) {
        const float* wp = usex ? pWi[g] : pWh[g];
        float4 wv = *(const float4*)&wp[k4 * 4];
        #pragma unroll
        for (int bb = 0; bb < 4; ++bb) {
          acc[g][bb] = fmaf(wv.x, ua[bb].x, acc[g][bb]);
          acc[g][bb] = fmaf(wv.y, ua[bb].y, acc[g][bb]);
          acc[g][bb] = fmaf(wv.z, ua[bb].z, acc[g][bb]);
          acc[g][bb] = fmaf(wv.w, ua[bb].w, acc[g][bb]);
        }
      }
      #pragma unroll
      for (int bb = 0; bb < 4; ++bb) ua[bb] = un[bb];
    }

    // pair-reduce kq (even,odd) in-wave, then stage to LDS
    float v[16];
    #pragma unroll
    for (int g = 0; g < 4; ++g)
      #pragma unroll
      for (int bb = 0; bb < 4; ++bb)
        v[g * 4 + bb] = acc[g][bb] + __shfl_xor(acc[g][bb], 32, 64);
    if ((tid & 32) == 0) {
      #pragma unroll
      for (int g = 0; g < 4; ++g)
        #pragma unroll
        for (int bb = 0; bb < 4; ++bb)
          red2[((kq >> 1) * 16 + g * 4 + jj) * 32 + bg * 4 + bb] = v[g * 4 + bb];
    }
    __syncthreads();

    if (tid < 128) {
      float gv[4];
      #pragma unroll
      for (int g = 0; g < 4; ++g) {
        float x = 0.0f;
        #pragma unroll
        for (int kh = 0; kh < 8; ++kh)
          x += red2[(kh * 16 + g * 4 + jj_u) * 32 + b_u];
        gv[g] = x + bs[g];
      }
      float c = sigf(gv[1]) * cst + sigf(gv[0]) * tanhf(gv[2]);
      cst = c;
      float h = sigf(gv[3]) * tanhf(c);
      stg1(&ucat[(((size_t)dir * 129 + s + 1) * NB + b_u) * 768 + 256 + j_u], h);
      if (dir == 0) {
        eo[((size_t)b_u * TE + s) * CTXD + j_u] = (s < Lu) ? h : 0.0f;
      } else {
        int pos = (s < Lu) ? (Lu - 1 - s) : s;
        eo[((size_t)b_u * TE + pos) * CTXD + HH + j_u] = (s < Lu) ? h : 0.0f;
      }
    }
    gbarT<16, 8>(bar, ob);
  }
}

// ---------------- Decoder: 64 blocks x 512 thr, persistent ----------------
// P2: block = (pb = bid>>1, half = bid&1): attn scores for batch pb + ctx d-half.
// P3: block handles GRU columns j0 = bid*8 .. +7, all 32 batches.
__global__ void __launch_bounds__(512)
dec_kernel(const int* __restrict__ dec_in, const int* __restrict__ lens,
           const float* __restrict__ emb_tgt,
           const float* __restrict__ gWih, const float* __restrict__ gWhh,
           const float* __restrict__ gbih, const float* __restrict__ gbhh,
           const float* __restrict__ attn_W, const float* __restrict__ attn_b,
           const float* __restrict__ attn_v,
           float* __restrict__ ws)
{
  int* bar = (int*)ws;
  float* eo = ws + OEO;
  float* ep = ws + OEP;
  float* hd = ws + OHD;
  float* cx = ws + OCX;

  const int tid = threadIdx.x;
  const int bid = blockIdx.x;

  asm volatile("buffer_inv sc1" ::: "memory");

  // pre-phase: epre[b][t][a] = enc_out@attn_W[:1024] + attn_b ; hdec[0]=0
  {
    const int gt = bid * 512 + tid;          // 0..32767, exactly NB*TE*8
    {
      int a = gt & 7;
      int t = (gt >> 3) & 127;
      int b = gt >> 10;
      float acc = attn_b[a];
      const float* er = &eo[((size_t)b * TE + t) * CTXD];
      for (int d = 0; d < CTXD; d += 4) {
        float4 ev = *(const float4*)&er[d];
        acc = fmaf(ev.x, attn_W[(d + 0) * 8 + a], acc);
        acc = fmaf(ev.y, attn_W[(d + 1) * 8 + a], acc);
        acc = fmaf(ev.z, attn_W[(d + 2) * 8 + a], acc);
        acc = fmaf(ev.w, attn_W[(d + 3) * 8 + a], acc);
      }
      stg1(&ep[gt], acc);
    }
    if (gt < NB * HH) stg1(&hd[gt], 0.0f);
  }
  gbarT<8, 8>(bar, bid);

  __shared__ float hpp[64];
  __shared__ float hpv[8];
  __shared__ float elds[128];
  __shared__ float wlds[128];
  __shared__ float red[64];

  const int pb   = bid >> 1;    // P2 batch
  const int half = bid & 1;     // P2 ctx d-half
  const int Lb   = lens[pb];

  // P3 mapping: c3 = column-in-block, b3 = batch, kh3 = k-half
  const int c3  = tid >> 6;
  const int b3  = (tid >> 1) & 31;
  const int kh3 = tid & 1;
  const int j3  = bid * 8 + c3;
  const float* pwi[3];
  const float* pwh[3];
  #pragma unroll
  for (int g = 0; g < 3; ++g) {
    pwi[g] = gWih + (size_t)(g * HH + j3) * (EMB + CTXD);
    pwh[g] = gWhh + (size_t)(g * HH + j3) * HH;
  }

  for (int s = 0; s < TD; ++s) {
    // ---- P2: attention scores, softmax, ctx ----
    {
      const float* hrow = &hd[(size_t)s * NB * HH + pb * HH];
      if (tid < 64) {
        int a = tid >> 3, p = tid & 7;
        float acc = 0.0f;
        const float* wp = &attn_W[(CTXD + p * 64) * 8 + a];
        const float* h8 = &hrow[p * 64];
        for (int q = 0; q < 64; ++q) acc = fmaf(h8[q], wp[q * 8], acc);
        hpp[tid] = acc;
      }
      __syncthreads();
      if (tid < 8) {
        float x = 0.0f;
        for (int p = 0; p < 8; ++p) x += hpp[tid * 8 + p];
        hpv[tid] = x;
      }
      __syncthreads();
      if (tid < 128) {
        float evv;
        if (tid < Lb) {
          evv = 0.0f;
          const float* e8 = &ep[((size_t)pb * TE + tid) * 8];
          #pragma unroll
          for (int a = 0; a < 8; ++a) evv += tanhf(e8[a] + hpv[a]) * attn_v[a];
        } else evv = -1e9f;
        elds[tid] = evv;
      }
      __syncthreads();
      if (tid < 64) red[tid] = fmaxf(elds[tid], elds[tid + 64]);
      __syncthreads();
      for (int w = 32; w > 0; w >>= 1) {
        if (tid < w) red[tid] = fmaxf(red[tid], red[tid + w]);
        __syncthreads();
      }
      float mx = red[0];
      __syncthreads();
      if (tid < 128) wlds[tid] = expf(elds[tid] - mx);
      __syncthreads();
      if (tid < 64) red[tid] = wlds[tid] + wlds[tid + 64];
      __syncthreads();
      for (int w = 32; w > 0; w >>= 1) {
        if (tid < w) red[tid] += red[tid + w];
        __syncthreads();
      }
      float inv = 1.0f / red[0];
      __syncthreads();
      {
        int d = half * 512 + tid;
        float acc = 0.0f;
        const float* ebase = &eo[(size_t)pb * TE * CTXD + d];
        #pragma unroll 4
        for (int t = 0; t < TE; ++t)
          acc = fmaf(wlds[t], ebase[(size_t)t * CTXD], acc);
        stg1(&cx[((size_t)s * NB + pb) * CTXD + d], acc * inv);
      }
    }
    gbarT<8, 8>(bar, bid);
    // ---- P3: GRU cell -> hdec[s+1] ----
    {
      int tok = dec_in[b3 * TD + s];
      const float* em  = &emb_tgt[(size_t)tok * EMB];
      const float* cxr = &cx[((size_t)s * NB + b3) * CTXD];
      const float* hr  = &hd[(size_t)s * NB * HH + b3 * HH];
      float ai[3] = {0.f, 0.f, 0.f};
      float ah[3] = {0.f, 0.f, 0.f};
      if (kh3 == 0) {
        for (int k = 0; k < 256; k += 4) {
          float4 xv = *(const float4*)&em[k];
          #pragma unroll
          for (int g = 0; g < 3; ++g) {
            float4 wv = *(const float4*)&pwi[g][k];
            ai[g] = fmaf(xv.x, wv.x, ai[g]); ai[g] = fmaf(xv.y, wv.y, ai[g]);
            ai[g] = fmaf(xv.z, wv.z, ai[g]); ai[g] = fmaf(xv.w, wv.w, ai[g]);
          }
        }
        for (int k = 256; k < 640; k += 4) {
          float4 xv = *(const float4*)&cxr[k - 256];
          #pragma unroll
          for (int g = 0; g < 3; ++g) {
            float4 wv = *(const float4*)&pwi[g][k];
            ai[g] = fmaf(xv.x, wv.x, ai[g]); ai[g] = fmaf(xv.y, wv.y, ai[g]);
            ai[g] = fmaf(xv.z, wv.z, ai[g]); ai[g] = fmaf(xv.w, wv.w, ai[g]);
          }
        }
        for (int k = 0; k < 256; k += 4) {
          float4 hv = *(const float4*)&hr[k];
          #pragma unroll
          for (int g = 0; g < 3; ++g) {
            float4 wv = *(const float4*)&pwh[g][k];
            ah[g] = fmaf(hv.x, wv.x, ah[g]); ah[g] = fmaf(hv.y, wv.y, ah[g]);
            ah[g] = fmaf(hv.z, wv.z, ah[g]); ah[g] = fmaf(hv.w, wv.w, ah[g]);
          }
        }
      } else {
        for (int k = 640; k < 1280; k += 4) {
          float4 xv = *(const float4*)&cxr[k - 256];
          #pragma unroll
          for (int g = 0; g < 3; ++g) {
            float4 wv = *(const float4*)&pwi[g][k];
            ai[g] = fmaf(xv.x, wv.x, ai[g]); ai[g] = fmaf(xv.y, wv.y, ai[g]);
            ai[g] = fmaf(xv.z, wv.z, ai[g]); ai[g] = fmaf(xv.w, wv.w, ai[g]);
          }
        }
        for (int k = 256; k < 512; k += 4) {
          float4 hv = *(const float4*)&hr[k];
          #pragma unroll
          for (int g = 0; g < 3; ++g) {
            float4 wv = *(const float4*)&pwh[g][k];
            ah[g] = fmaf(hv.x, wv.x, ah[g]); ah[g] = fmaf(hv.y, wv.y, ah[g]);
            ah[g] = fmaf(hv.z, wv.z, ah[g]); ah[g] = fmaf(hv.w, wv.w, ah[g]);
          }
        }
      }
      float gi[3], gh[3];
      #pragma unroll
      for (int g = 0; g < 3; ++g) {
        gi[g] = ai[g] + __shfl_xor(ai[g], 1, 64);
        gh[g] = ah[g] + __shfl_xor(ah[g], 1, 64);
      }
      if (kh3 == 0) {
        float r = sigf(gi[0] + gbih[j3]          + gh[0] + gbhh[j3]);
        float z = sigf(gi[1] + gbih[HH + j3]     + gh[1] + gbhh[HH + j3]);
        float n = tanhf(gi[2] + gbih[2 * HH + j3] + r * (gh[2] + gbhh[2 * HH + j3]));
        float hold = hr[j3];
        float hnew = (1.0f - z) * n + z * hold;
        stg1(&hd[(size_t)(s + 1) * NB * HH + b3 * HH + j3], hnew);
      }
    }
    gbarT<8, 8>(bar, bid);
  }
}

// ---------------- Classifier: [1024,512] @ clf_W^T [512,32000], relu ----------------
__global__ void __launch_bounds__(256)
clf_kernel(const float* __restrict__ hdec, const float* __restrict__ W,
           const float* __restrict__ bias, float* __restrict__ out)
{
  asm volatile("buffer_inv sc1" ::: "memory");  // stale-clean-line insurance (replays)
  __shared__ __align__(16) float As[16][68];
  __shared__ __align__(16) float Bs[16][68];
  const int tid = threadIdx.x;
  const int tx = tid & 15, ty = tid >> 4;
  const int n0 = blockIdx.x * 64, m0 = blockIdx.y * 64;
  float acc[4][4] = {};
  const int lr = tid >> 2;
  const int lk = (tid & 3) * 4;
  const int r  = m0 + lr;                       // r = b*TD + t
  const float* arow = hdec + (((size_t)(r & 31) + 1) * NB + (r >> 5)) * HH;
  const float* brow = W + (size_t)(n0 + lr) * HH;

  for (int kc = 0; kc < HH; kc += 16) {
    float4 av = *(const float4*)&arow[kc + lk];
    float4 bv = *(const float4*)&brow[kc + lk];
    __syncthreads();
    As[lk + 0][lr] = av.x; As[lk + 1][lr] = av.y;
    As[lk + 2][lr] = av.z; As[lk + 3][lr] = av.w;
    Bs[lk + 0][lr] = bv.x; Bs[lk + 1][lr] = bv.y;
    Bs[lk + 2][lr] = bv.z; Bs[lk + 3][lr] = bv.w;
    __syncthreads();
    #pragma unroll
    for (int kk = 0; kk < 16; ++kk) {
      float4 a4 = *(const float4*)&As[kk][ty * 4];
      float4 b4 = *(const float4*)&Bs[kk][tx * 4];
      acc[0][0] = fmaf(a4.x, b4.x, acc[0][0]); acc[0][1] = fmaf(a4.x, b4.y, acc[0][1]);
      acc[0][2] = fmaf(a4.x, b4.z, acc[0][2]); acc[0][3] = fmaf(a4.x, b4.w, acc[0][3]);
      acc[1][0] = fmaf(a4.y, b4.x, acc[1][0]); acc[1][1] = fmaf(a4.y, b4.y, acc[1][1]);
      acc[1][2] = fmaf(a4.y, b4.z, acc[1][2]); acc[1][3] = fmaf(a4.y, b4.w, acc[1][3]);
      acc[2][0] = fmaf(a4.z, b4.x, acc[2][0]); acc[2][1] = fmaf(a4.z, b4.y, acc[2][1]);
      acc[2][2] = fmaf(a4.z, b4.z, acc[2][2]); acc[2][3] = fmaf(a4.z, b4.w, acc[2][3]);
      acc[3][0] = fmaf(a4.w, b4.x, acc[3][0]); acc[3][1] = fmaf(a4.w, b4.y, acc[3][1]);
      acc[3][2] = fmaf(a4.w, b4.z, acc[3][2]); acc[3][3] = fmaf(a4.w, b4.w, acc[3][3]);
    }
  }
  const int col = n0 + tx * 4;
  float4 bb4 = *(const float4*)&bias[col];
  #pragma unroll
  for (int i = 0; i < 4; ++i) {
    int row = m0 + ty * 4 + i;
    float4 o;
    o.x = fmaxf(acc[i][0] + bb4.x, 0.0f);
    o.y = fmaxf(acc[i][1] + bb4.y, 0.0f);
    o.z = fmaxf(acc[i][2] + bb4.z, 0.0f);
    o.w = fmaxf(acc[i][3] + bb4.w, 0.0f);
    *(float4*)&out[(size_t)row * VOC + col] = o;
  }
}

extern "C" void kernel_launch(void* const* d_in, const int* in_sizes, int n_in,
                              void* d_out, int out_size, void* d_ws, size_t ws_size,
                              hipStream_t stream)
{
  if (ws_size < (size_t)WSEND * 4) return;  // visible-failure guard

  const int* enc_in  = (const int*)d_in[0];
  const int* enc_len = (const int*)d_in[1];
  const int* dec_in  = (const int*)d_in[2];
  const float* emb_src = (const float*)d_in[4];
  const float* emb_tgt = (const float*)d_in[5];
  const float* Wih_f = (const float*)d_in[6];
  const float* Whh_f = (const float*)d_in[7];
  const float* bih_f = (const float*)d_in[8];
  const float* bhh_f = (const float*)d_in[9];
  const float* Wih_b = (const float*)d_in[10];
  const float* Whh_b = (const float*)d_in[11];
  const float* bih_b = (const float*)d_in[12];
  const float* bhh_b = (const float*)d_in[13];
  const float* gWih  = (const float*)d_in[14];
  const float* gWhh  = (const float*)d_in[15];
  const float* gbih  = (const float*)d_in[16];
  const float* gbhh  = (const float*)d_in[17];
  const float* attn_W = (const float*)d_in[18];
  const float* attn_b = (const float*)d_in[19];
  const float* attn_v = (const float*)d_in[20];
  const float* clf_W = (const float*)d_in[21];
  const float* clf_b = (const float*)d_in[22];
  float* ws  = (float*)d_ws;
  float* out = (float*)d_out;

  hipMemsetAsync(d_ws, 0, 8192, stream);  // barrier state (2 regions x 4KB)
  scan_kernel<<<256, 512, 0, stream>>>(enc_in, enc_len, emb_src,
      Wih_f, Whh_f, bih_f, bhh_f, Wih_b, Whh_b, bih_b, bhh_b, ws);
  dec_kernel<<<64, 512, 0, stream>>>(dec_in, enc_len, emb_tgt,
      gWih, gWhh, gbih, gbhh, attn_W, attn_b, attn_v, ws);
  dim3 cg(VOC / 64, (NB * TD) / 64);
  clf_kernel<<<cg, 256, 0, stream>>>(ws + OHD, clf_W, clf_b, out);
}

// Round 4
// 6817.814 us; speedup vs baseline: 1.7330x; 1.4662x over previous
//
#include <hip/hip_runtime.h>
#include <cmath>

#define NB   32
#define TE   128
#define TD   32
#define VOC  32000
#define EMB  256
#define HH   512
#define CTXD 1024
#define DCW  1536   // dcat row: [ctx 1024 | h 512]

// ws float offsets. ints 0..1023 = barrier regions (scan d0 @0, scan d1 @256, dec @512)
#define OHS  1024                        // harr [2][129][NB][HH]
#define OEO  (OHS + 2*129*NB*HH)         // enc_out [NB][TE][CTXD]
#define OEP  (OEO + NB*TE*CTXD)          // epre [NB][TE][8]
#define ODC  (OEP + NB*TE*8)             // dcat [TD+1][NB][DCW]
#define WSEND (ODC + (TD+1)*NB*DCW)      // 10,077,184 floats ~40.3MB

__device__ __forceinline__ float sigf(float x) { return 1.0f / (1.0f + expf(-x)); }

__device__ __forceinline__ void stg1(float* p, float v) {
  __hip_atomic_store(p, v, __ATOMIC_RELAXED, __HIP_MEMORY_SCOPE_AGENT);
}

__device__ __forceinline__ void fma4(float4& a, const float4 w, const float4 u) {
  a.x = fmaf(w.x, u.x, a.x); a.y = fmaf(w.y, u.y, a.y);
  a.z = fmaf(w.z, u.z, a.z); a.w = fmaf(w.w, u.w, a.w);
}

// Flat all-relaxed grid barrier (no acquire anywhere: agent-acquire emits
// buffer_inv sc1 = L2 nuke, R2's regression). Data correctness: sc1 stores +
// syncthreads vmcnt-drain before arrival; readers touch per-step-fresh addrs.
template<int N>
__device__ __forceinline__ void gbarF(int* bar) {
  __syncthreads();
  if (threadIdx.x == 0) {
    int* cnt = bar;
    int* gen = bar + 16;
    int g = __hip_atomic_load(gen, __ATOMIC_RELAXED, __HIP_MEMORY_SCOPE_AGENT);
    int v = __hip_atomic_fetch_add(cnt, 1, __ATOMIC_RELAXED, __HIP_MEMORY_SCOPE_AGENT);
    if (v == N - 1) {
      __hip_atomic_store(cnt, 0, __ATOMIC_RELAXED, __HIP_MEMORY_SCOPE_AGENT);
      asm volatile("s_waitcnt vmcnt(0)" ::: "memory");   // reset lands before gen bump
      __hip_atomic_fetch_add(gen, 1, __ATOMIC_RELAXED, __HIP_MEMORY_SCOPE_AGENT);
    } else {
      int it = 0;
      while (__hip_atomic_load(gen, __ATOMIC_RELAXED, __HIP_MEMORY_SCOPE_AGENT) == g) {
        __builtin_amdgcn_s_sleep(2);
        if (++it > (1 << 22)) break;  // safety bail: garbage beats hang
      }
    }
  }
  __syncthreads();
}

// ---------------- BiLSTM scan: 256 blocks x 512 thr, persistent ----------------
// dir = bid>>7 (independent 128-block halves, own barrier region).
// block ob: h-columns j0=ob*4..+3 (16 gate-rows). wave = 2 rows; lane = bq*16+kl
// (4 batches x 16 k-lanes). Weights (24 float4/wave) preloaded in VGPRs ONCE.
__global__ void __launch_bounds__(512)
scan_kernel(const int* __restrict__ enc_in, const int* __restrict__ lens,
            const float* __restrict__ emb_src,
            const float* __restrict__ Wih_f, const float* __restrict__ Whh_f,
            const float* __restrict__ bih_f, const float* __restrict__ bhh_f,
            const float* __restrict__ Wih_b, const float* __restrict__ Whh_b,
            const float* __restrict__ bih_b, const float* __restrict__ bhh_b,
            float* __restrict__ ws)
{
  const int tid = threadIdx.x, bid = blockIdx.x;
  const int dir = bid >> 7, ob = bid & 127;
  int* bar = (int*)ws + dir * 256;
  float* harr = ws + OHS;
  float* eo   = ws + OEO;

  asm volatile("buffer_inv sc1" ::: "memory");  // purge stale clean lines (graph replays)

  __shared__ int tokL[TE * NB];
  __shared__ float lds_g[16][33];

  // pre-phase: per-block token table (LDS) + zero own h0 slice
  for (int i = tid; i < TE * NB; i += 512) {
    int b = i & 31, s = i >> 5;
    int t = s;
    if (dir) { int L = lens[b]; t = (s < L) ? (L - 1 - s) : s; }
    tokL[i] = enc_in[b * TE + t];
  }
  if (tid < 128) {
    int b = tid >> 2, jj = tid & 3;
    stg1(&harr[((size_t)(dir * 129) * NB + b) * HH + ob * 4 + jj], 0.0f);
  }

  const int lane = tid & 63, w = tid >> 6;
  const int bq = lane >> 4, kl = lane & 15;
  const float* Wih = dir ? Wih_b : Wih_f;
  const float* Whh = dir ? Whh_b : Whh_f;
  const int r0 = 2 * w, r1 = 2 * w + 1;            // rows r = g*4 + jj
  const int o0 = (r0 >> 2) * HH + ob * 4 + (r0 & 3);
  const int o1 = (r1 >> 2) * HH + ob * 4 + (r1 & 3);
  float4 W0[12], W1[12];
  #pragma unroll
  for (int c = 0; c < 12; ++c) {
    W0[c] = (c < 4) ? *(const float4*)&Wih[(size_t)o0 * EMB + c * 64 + kl * 4]
                    : *(const float4*)&Whh[(size_t)o0 * HH + (c - 4) * 64 + kl * 4];
    W1[c] = (c < 4) ? *(const float4*)&Wih[(size_t)o1 * EMB + c * 64 + kl * 4]
                    : *(const float4*)&Whh[(size_t)o1 * HH + (c - 4) * 64 + kl * 4];
  }

  // updater role (tid<128): (b_u, jj_u); carries c-state in register
  const int b_u = tid >> 2, jj_u = tid & 3;
  const int j_u = ob * 4 + jj_u;
  int Lu = 0;
  float bs0 = 0.f, bs1 = 0.f, bs2 = 0.f, bs3 = 0.f;
  if (tid < 128) {
    Lu = lens[b_u];
    const float* bih = dir ? bih_b : bih_f;
    const float* bhh = dir ? bhh_b : bhh_f;
    bs0 = bih[0 * HH + j_u] + bhh[0 * HH + j_u];
    bs1 = bih[1 * HH + j_u] + bhh[1 * HH + j_u];
    bs2 = bih[2 * HH + j_u] + bhh[2 * HH + j_u];
    bs3 = bih[3 * HH + j_u] + bhh[3 * HH + j_u];
  }
  float cst = 0.0f;

  gbarF<128>(bar);

  for (int s = 0; s < TE; ++s) {
    const float* hbase = harr + ((size_t)(dir * 129 + s) * NB) * HH;
    for (int bg = 0; bg < 8; ++bg) {
      int b = bg * 4 + bq;
      int tok = tokL[s * 32 + b];
      const float* xr = emb_src + (size_t)tok * EMB + kl * 4;
      const float* hr = hbase + (size_t)b * HH + kl * 4;
      float4 a0a = {0,0,0,0}, a0b = {0,0,0,0}, a1a = {0,0,0,0}, a1b = {0,0,0,0};
      #pragma unroll
      for (int c = 0; c < 12; ++c) {
        float4 u = (c < 4) ? *(const float4*)&xr[c * 64]
                           : *(const float4*)&hr[(c - 4) * 64];
        if (c & 1) { fma4(a0b, W0[c], u); fma4(a1b, W1[c], u); }
        else       { fma4(a0a, W0[c], u); fma4(a1a, W1[c], u); }
      }
      float s0 = (a0a.x + a0a.y + a0a.z + a0a.w) + (a0b.x + a0b.y + a0b.z + a0b.w);
      float s1 = (a1a.x + a1a.y + a1a.z + a1a.w) + (a1b.x + a1b.y + a1b.z + a1b.w);
      s0 += __shfl_xor(s0, 1); s1 += __shfl_xor(s1, 1);
      s0 += __shfl_xor(s0, 2); s1 += __shfl_xor(s1, 2);
      s0 += __shfl_xor(s0, 4); s1 += __shfl_xor(s1, 4);
      s0 += __shfl_xor(s0, 8); s1 += __shfl_xor(s1, 8);
      if (kl == 0) { lds_g[r0][b] = s0; lds_g[r1][b] = s1; }
    }
    __syncthreads();
    if (tid < 128) {
      float gi = lds_g[0  + jj_u][b_u] + bs0;
      float gf = lds_g[4  + jj_u][b_u] + bs1;
      float gg = lds_g[8  + jj_u][b_u] + bs2;
      float go = lds_g[12 + jj_u][b_u] + bs3;
      float c = sigf(gf) * cst + sigf(gi) * tanhf(gg);
      cst = c;
      float h = sigf(go) * tanhf(c);
      stg1(&harr[((size_t)(dir * 129 + s + 1) * NB + b_u) * HH + j_u], h);
      float hm = (s < Lu) ? h : 0.0f;
      int pos = dir ? ((s < Lu) ? (Lu - 1 - s) : s) : s;
      eo[((size_t)b_u * TE + pos) * CTXD + dir * HH + j_u] = hm;
    }
    gbarF<128>(bar);
  }
}

// ---------------- Decoder: 256 blocks x 512 thr, persistent ----------------
// P2: block (pb=bid>>3, ds=bid&7): redundant scores+softmax, own 128-d ctx slice.
// P3: block owns GRU columns j = 2*bid, 2*bid+1; waves 0..5 = one gate-row each
// (28 float4 weights in VGPRs, preloaded once); lane = bq*16+kl.
__global__ void __launch_bounds__(512)
dec_kernel(const int* __restrict__ dec_in, const int* __restrict__ lens,
           const float* __restrict__ emb_tgt,
           const float* __restrict__ gWih, const float* __restrict__ gWhh,
           const float* __restrict__ gbih, const float* __restrict__ gbhh,
           const float* __restrict__ attn_W, const float* __restrict__ attn_b,
           const float* __restrict__ attn_v,
           float* __restrict__ ws)
{
  const int tid = threadIdx.x, bid = blockIdx.x;
  int* bar = (int*)ws + 512;
  float* eo   = ws + OEO;
  float* ep   = ws + OEP;
  float* dcat = ws + ODC;

  asm volatile("buffer_inv sc1" ::: "memory");

  __shared__ int tokD[TD * NB];
  __shared__ float av8[8];
  __shared__ float hpv[8];
  __shared__ float elds[128];
  __shared__ float wlds[128];
  __shared__ float redL[2];
  __shared__ float cpart[4][128];
  __shared__ float lds_d[2][6][33];

  for (int i = tid; i < TD * NB; i += 512) {
    int b = i & 31, s = i >> 5;
    tokD[i] = dec_in[b * TD + s];
  }
  if (tid < 8) av8[tid] = attn_v[tid];

  // pre-phase: ep = enc_out @ attn_W[:1024] + attn_b (blocks 0..63); zero h0 (64..95)
  {
    const int gt = bid * 512 + tid;
    if (gt < NB * TE * 8) {
      int a = gt & 7, t = (gt >> 3) & 127, b = gt >> 10;
      float acc = attn_b[a];
      const float* er = &eo[((size_t)b * TE + t) * CTXD];
      for (int d = 0; d < CTXD; d += 4) {
        float4 ev = *(const float4*)&er[d];
        acc = fmaf(ev.x, attn_W[(d + 0) * 8 + a], acc);
        acc = fmaf(ev.y, attn_W[(d + 1) * 8 + a], acc);
        acc = fmaf(ev.z, attn_W[(d + 2) * 8 + a], acc);
        acc = fmaf(ev.w, attn_W[(d + 3) * 8 + a], acc);
      }
      stg1(&ep[gt], acc);
    }
    int g2 = gt - NB * TE * 8;
    if (g2 >= 0 && g2 < NB * HH) {
      int b = g2 >> 9, j = g2 & 511;
      stg1(&dcat[(size_t)b * DCW + CTXD + j], 0.0f);
    }
  }

  const int pb = bid >> 3, ds = bid & 7;
  const int Lb = lens[pb];
  const int lane = tid & 63, w = tid >> 6;
  const int bq = lane >> 4, kl = lane & 15;

  // P3 weights: row = g*HH + 2*bid + jl, g = w>>1, jl = w&1
  float4 WD[28];
  if (w < 6) {
    const int row = (w >> 1) * HH + bid * 2 + (w & 1);
    #pragma unroll
    for (int c = 0; c < 28; ++c) {
      WD[c] = (c < 20) ? *(const float4*)&gWih[(size_t)row * (EMB + CTXD) + c * 64 + kl * 4]
                       : *(const float4*)&gWhh[(size_t)row * HH + (c - 20) * 64 + kl * 4];
    }
  }
  // updater (tid<64): (b_u, jl_u), carries h in register
  const int b_u = tid & 31, jl_u = tid >> 5;
  const int j_u = bid * 2 + jl_u;
  float bRi = 0, bRh = 0, bZi = 0, bZh = 0, bNi = 0, bNh = 0;
  if (tid < 64) {
    bRi = gbih[j_u];          bRh = gbhh[j_u];
    bZi = gbih[HH + j_u];     bZh = gbhh[HH + j_u];
    bNi = gbih[2 * HH + j_u]; bNh = gbhh[2 * HH + j_u];
  }
  float hreg = 0.0f;

  gbarF<256>(bar);

  for (int s = 0; s < TD; ++s) {
    // ---- P2: scores (redundant per ds), softmax, ctx slice ----
    const float* hrow = dcat + ((size_t)s * NB + pb) * DCW + CTXD;
    {
      // hpv[a=w] = sum_k h[k] * attn_W[1024+k][a]
      float acc = 0.0f;
      const float4* h4 = (const float4*)hrow;
      float4 ha = h4[lane * 2], hb = h4[lane * 2 + 1];
      const float* wa = attn_W + (size_t)(CTXD + lane * 8) * 8 + w;
      acc = fmaf(ha.x, wa[0],  acc); acc = fmaf(ha.y, wa[8],  acc);
      acc = fmaf(ha.z, wa[16], acc); acc = fmaf(ha.w, wa[24], acc);
      acc = fmaf(hb.x, wa[32], acc); acc = fmaf(hb.y, wa[40], acc);
      acc = fmaf(hb.z, wa[48], acc); acc = fmaf(hb.w, wa[56], acc);
      acc += __shfl_xor(acc, 1);  acc += __shfl_xor(acc, 2);
      acc += __shfl_xor(acc, 4);  acc += __shfl_xor(acc, 8);
      acc += __shfl_xor(acc, 16); acc += __shfl_xor(acc, 32);
      if (lane == 0) hpv[w] = acc;
    }
    __syncthreads();
    if (tid < 128) {
      float evv = -1e9f;
      if (tid < Lb) {
        const float* e8 = &ep[((size_t)pb * TE + tid) * 8];
        float4 ea = *(const float4*)e8, eb = *(const float4*)(e8 + 4);
        evv  = tanhf(ea.x + hpv[0]) * av8[0];
        evv += tanhf(ea.y + hpv[1]) * av8[1];
        evv += tanhf(ea.z + hpv[2]) * av8[2];
        evv += tanhf(ea.w + hpv[3]) * av8[3];
        evv += tanhf(eb.x + hpv[4]) * av8[4];
        evv += tanhf(eb.y + hpv[5]) * av8[5];
        evv += tanhf(eb.z + hpv[6]) * av8[6];
        evv += tanhf(eb.w + hpv[7]) * av8[7];
      }
      elds[tid] = evv;
    }
    __syncthreads();
    if (tid < 64) {
      float m = fmaxf(elds[tid], elds[tid + 64]);
      m = fmaxf(m, __shfl_xor(m, 1));  m = fmaxf(m, __shfl_xor(m, 2));
      m = fmaxf(m, __shfl_xor(m, 4));  m = fmaxf(m, __shfl_xor(m, 8));
      m = fmaxf(m, __shfl_xor(m, 16)); m = fmaxf(m, __shfl_xor(m, 32));
      if (tid == 0) redL[0] = m;
    }
    __syncthreads();
    float mx = redL[0];
    if (tid < 128) wlds[tid] = expf(elds[tid] - mx);
    __syncthreads();
    if (tid < 64) {
      float sm = wlds[tid] + wlds[tid + 64];
      sm += __shfl_xor(sm, 1);  sm += __shfl_xor(sm, 2);
      sm += __shfl_xor(sm, 4);  sm += __shfl_xor(sm, 8);
      sm += __shfl_xor(sm, 16); sm += __shfl_xor(sm, 32);
      if (tid == 0) redL[1] = 1.0f / sm;
    }
    {
      const int d = tid & 127, tq = tid >> 7;
      float acc = 0.0f;
      const float* eb = eo + ((size_t)pb * TE + tq * 32) * CTXD + ds * 128 + d;
      #pragma unroll 4
      for (int t = 0; t < 32; ++t)
        acc = fmaf(wlds[tq * 32 + t], eb[(size_t)t * CTXD], acc);
      cpart[tq][d] = acc;
    }
    __syncthreads();
    if (tid < 128) {
      float c = (cpart[0][tid] + cpart[1][tid] + cpart[2][tid] + cpart[3][tid]) * redL[1];
      stg1(&dcat[((size_t)s * NB + pb) * DCW + ds * 128 + tid], c);
    }
    gbarF<256>(bar);

    // ---- P3: GRU gate dots (waves 0..5), update (tid<64) ----
    if (w < 6) {
      for (int bg = 0; bg < 8; ++bg) {
        int b = bg * 4 + bq;
        int tok = tokD[s * 32 + b];
        const float* xr = emb_tgt + (size_t)tok * EMB + kl * 4;
        const float* cr = dcat + ((size_t)s * NB + b) * DCW + kl * 4;
        const float* hr = cr + CTXD;
        float4 aia = {0,0,0,0}, aib = {0,0,0,0}, aha = {0,0,0,0}, ahb = {0,0,0,0};
        #pragma unroll
        for (int c = 0; c < 28; ++c) {
          float4 u = (c < 4)  ? *(const float4*)&xr[c * 64]
                   : (c < 20) ? *(const float4*)&cr[(c - 4) * 64]
                              : *(const float4*)&hr[(c - 20) * 64];
          if (c < 20) { if (c & 1) fma4(aib, WD[c], u); else fma4(aia, WD[c], u); }
          else        { if (c & 1) fma4(ahb, WD[c], u); else fma4(aha, WD[c], u); }
        }
        float si = (aia.x + aia.y + aia.z + aia.w) + (aib.x + aib.y + aib.z + aib.w);
        float sh = (aha.x + aha.y + aha.z + aha.w) + (ahb.x + ahb.y + ahb.z + ahb.w);
        si += __shfl_xor(si, 1); sh += __shfl_xor(sh, 1);
        si += __shfl_xor(si, 2); sh += __shfl_xor(sh, 2);
        si += __shfl_xor(si, 4); sh += __shfl_xor(sh, 4);
        si += __shfl_xor(si, 8); sh += __shfl_xor(sh, 8);
        if (kl == 0) { lds_d[0][w][b] = si; lds_d[1][w][b] = sh; }
      }
    }
    __syncthreads();
    if (tid < 64) {
      float giR = lds_d[0][0 + jl_u][b_u], ghR = lds_d[1][0 + jl_u][b_u];
      float giZ = lds_d[0][2 + jl_u][b_u], ghZ = lds_d[1][2 + jl_u][b_u];
      float giN = lds_d[0][4 + jl_u][b_u], ghN = lds_d[1][4 + jl_u][b_u];
      float r = sigf(giR + bRi + ghR + bRh);
      float z = sigf(giZ + bZi + ghZ + bZh);
      float n = tanhf(giN + bNi + r * (ghN + bNh));
      float hnew = (1.0f - z) * n + z * hreg;
      hreg = hnew;
      stg1(&dcat[((size_t)(s + 1) * NB + b_u) * DCW + CTXD + j_u], hnew);
    }
    gbarF<256>(bar);
  }
}

// ---------------- Classifier: [1024,512] @ clf_W^T [512,32000], relu ----------------
__global__ void __launch_bounds__(256)
clf_kernel(const float* __restrict__ dcat, const float* __restrict__ W,
           const float* __restrict__ bias, float* __restrict__ out)
{
  asm volatile("buffer_inv sc1" ::: "memory");  // stale-clean-line insurance (replays)
  __shared__ __align__(16) float As[16][68];
  __shared__ __align__(16) float Bs[16][68];
  const int tid = threadIdx.x;
  const int tx = tid & 15, ty = tid >> 4;
  const int n0 = blockIdx.x * 64, m0 = blockIdx.y * 64;
  float acc[4][4] = {};
  const int lr = tid >> 2;
  const int lk = (tid & 3) * 4;
  const int r  = m0 + lr;                       // r = b*TD + t
  const float* arow = dcat + ((size_t)((r & 31) + 1) * NB + (r >> 5)) * DCW + CTXD;
  const float* brow = W + (size_t)(n0 + lr) * HH;

  for (int kc = 0; kc < HH; kc += 16) {
    float4 av = *(const float4*)&arow[kc + lk];
    float4 bv = *(const float4*)&brow[kc + lk];
    __syncthreads();
    As[lk + 0][lr] = av.x; As[lk + 1][lr] = av.y;
    As[lk + 2][lr] = av.z; As[lk + 3][lr] = av.w;
    Bs[lk + 0][lr] = bv.x; Bs[lk + 1][lr] = bv.y;
    Bs[lk + 2][lr] = bv.z; Bs[lk + 3][lr] = bv.w;
    __syncthreads();
    #pragma unroll
    for (int kk = 0; kk < 16; ++kk) {
      float4 a4 = *(const float4*)&As[kk][ty * 4];
      float4 b4 = *(const float4*)&Bs[kk][tx * 4];
      acc[0][0] = fmaf(a4.x, b4.x, acc[0][0]); acc[0][1] = fmaf(a4.x, b4.y, acc[0][1]);
      acc[0][2] = fmaf(a4.x, b4.z, acc[0][2]); acc[0][3] = fmaf(a4.x, b4.w, acc[0][3]);
      acc[1][0] = fmaf(a4.y, b4.x, acc[1][0]); acc[1][1] = fmaf(a4.y, b4.y, acc[1][1]);
      acc[1][2] = fmaf(a4.y, b4.z, acc[1][2]); acc[1][3] = fmaf(a4.y, b4.w, acc[1][3]);
      acc[2][0] = fmaf(a4.z, b4.x, acc[2][0]); acc[2][1] = fmaf(a4.z, b4.y, acc[2][1]);
      acc[2][2] = fmaf(a4.z, b4.z, acc[2][2]); acc[2][3] = fmaf(a4.z, b4.w, acc[2][3]);
      acc[3][0] = fmaf(a4.w, b4.x, acc[3][0]); acc[3][1] = fmaf(a4.w, b4.y, acc[3][1]);
      acc[3][2] = fmaf(a4.w, b4.z, acc[3][2]); acc[3][3] = fmaf(a4.w, b4.w, acc[3][3]);
    }
  }
  const int col = n0 + tx * 4;
  float4 bb4 = *(const float4*)&bias[col];
  #pragma unroll
  for (int i = 0; i < 4; ++i) {
    int row = m0 + ty * 4 + i;
    float4 o;
    o.x = fmaxf(acc[i][0] + bb4.x, 0.0f);
    o.y = fmaxf(acc[i][1] + bb4.y, 0.0f);
    o.z = fmaxf(acc[i][2] + bb4.z, 0.0f);
    o.w = fmaxf(acc[i][3] + bb4.w, 0.0f);
    *(float4*)&out[(size_t)row * VOC + col] = o;
  }
}

extern "C" void kernel_launch(void* const* d_in, const int* in_sizes, int n_in,
                              void* d_out, int out_size, void* d_ws, size_t ws_size,
                              hipStream_t stream)
{
  if (ws_size < (size_t)WSEND * 4) return;  // visible-failure guard

  const int* enc_in  = (const int*)d_in[0];
  const int* enc_len = (const int*)d_in[1];
  const int* dec_in  = (const int*)d_in[2];
  const float* emb_src = (const float*)d_in[4];
  const float* emb_tgt = (const float*)d_in[5];
  const float* Wih_f = (const float*)d_in[6];
  const float* Whh_f = (const float*)d_in[7];
  const float* bih_f = (const float*)d_in[8];
  const float* bhh_f = (const float*)d_in[9];
  const float* Wih_b = (const float*)d_in[10];
  const float* Whh_b = (const float*)d_in[11];
  const float* bih_b = (const float*)d_in[12];
  const float* bhh_b = (const float*)d_in[13];
  const float* gWih  = (const float*)d_in[14];
  const float* gWhh  = (const float*)d_in[15];
  const float* gbih  = (const float*)d_in[16];
  const float* gbhh  = (const float*)d_in[17];
  const float* attn_W = (const float*)d_in[18];
  const float* attn_b = (const float*)d_in[19];
  const float* attn_v = (const float*)d_in[20];
  const float* clf_W = (const float*)d_in[21];
  const float* clf_b = (const float*)d_in[22];
  float* ws  = (float*)d_ws;
  float* out = (float*)d_out;

  hipMemsetAsync(d_ws, 0, 4096, stream);  // barrier state (3 regions in 1024 ints)
  scan_kernel<<<256, 512, 0, stream>>>(enc_in, enc_len, emb_src,
      Wih_f, Whh_f, bih_f, bhh_f, Wih_b, Whh_b, bih_b, bhh_b, ws);
  dec_kernel<<<256, 512, 0, stream>>>(dec_in, enc_len, emb_tgt,
      gWih, gWhh, gbih, gbhh, attn_W, attn_b, attn_v, ws);
  dim3 cg(VOC / 64, (NB * TD) / 64);
  clf_kernel<<<cg, 256, 0, stream>>>(ws + ODC, clf_W, clf_b, out);
}

// Round 5
// 6553.886 us; speedup vs baseline: 1.8027x; 1.0403x over previous
//
#include <hip/hip_runtime.h>
#include <cmath>

#define NB   32
#define TE   128
#define TD   32
#define VOC  32000
#define EMB  256
#define HH   512
#define CTXD 1024
#define DCW  1536   // dcat row: [ctx 1024 | h 512]

// ws float offsets. ints: cnt_d0 @0, cnt_d1 @64, dec cnt @128 (monotonic counters)
#define OHS  1024                        // harr [2][129][NB][HH]
#define OEO  (OHS + 2*129*NB*HH)         // enc_out [NB][TE][CTXD]
#define OEP  (OEO + NB*TE*CTXD)          // epre [NB][TE][8]
#define ODC  (OEP + NB*TE*8)             // dcat [TD+1][NB][DCW]
#define WSEND (ODC + (TD+1)*NB*DCW)      // ~40.3MB

__device__ __forceinline__ float sigf(float x) { return 1.0f / (1.0f + expf(-x)); }
__device__ __forceinline__ float hsum4(float4 v) { return (v.x + v.y) + (v.z + v.w); }

__device__ __forceinline__ void stg1(float* p, float v) {
  __hip_atomic_store(p, v, __ATOMIC_RELAXED, __HIP_MEMORY_SCOPE_AGENT);
}

__device__ __forceinline__ void fma4(float4& a, const float4 w, const float4 u) {
  a.x = fmaf(w.x, u.x, a.x); a.y = fmaf(w.y, u.y, a.y);
  a.z = fmaf(w.z, u.z, a.z); a.w = fmaf(w.w, u.w, a.w);
}

// Monotonic single-line barrier: one RMW; pollers wait cnt>=target; last arriver
// skips polling. All-relaxed (agent-acquire would buffer_inv sc1 = L2 nuke).
// Data correctness: __syncthreads drains vmcnt (sc1 stores at L3) before RMW;
// cross-block data read at per-step-fresh addresses only.
__device__ __forceinline__ void gbarM(int* cnt, int target) {
  __syncthreads();
  if (threadIdx.x == 0) {
    int v = __hip_atomic_fetch_add(cnt, 1, __ATOMIC_RELAXED, __HIP_MEMORY_SCOPE_AGENT);
    if (v != target - 1) {
      int it = 0;
      while (__hip_atomic_load(cnt, __ATOMIC_RELAXED, __HIP_MEMORY_SCOPE_AGENT) < target) {
        __builtin_amdgcn_s_sleep(1);
        if (++it > (1 << 20)) break;  // safety bail: garbage beats hang
      }
    }
  }
  __syncthreads();
}

// ---------------- BiLSTM scan: 256 blocks x 512 thr, persistent ----------------
// dir = bid>>7 (independent 128-block halves, own counter). Block ob: h-columns
// ob*4..+3 (16 gate-rows r = g*4+jj). Wave w: rows r0=2w,r1=2w+1; lane = bq*16+kl.
// Whh h-part in VGPRs (16 float4/wave). x@Wih+bias precomputed per 16-step chunk
// into LDS xpre (recurrence critical path = h@Whh only).
__global__ void __launch_bounds__(512)
scan_kernel(const int* __restrict__ enc_in, const int* __restrict__ lens,
            const float* __restrict__ emb_src,
            const float* __restrict__ Wih_f, const float* __restrict__ Whh_f,
            const float* __restrict__ bih_f, const float* __restrict__ bhh_f,
            const float* __restrict__ Wih_b, const float* __restrict__ Whh_b,
            const float* __restrict__ bih_b, const float* __restrict__ bhh_b,
            float* __restrict__ ws)
{
  const int tid = threadIdx.x, bid = blockIdx.x;
  const int dir = bid >> 7, ob = bid & 127;
  int* cnt = (int*)ws + dir * 64;
  float* harr = ws + OHS;
  float* eo   = ws + OEO;

  asm volatile("buffer_inv sc1" ::: "memory");  // purge stale clean lines (graph replays)

  __shared__ int   tokL[TE * NB];            // 16 KB
  __shared__ float xpre[16][NB][16];         // 32 KB  [ss][b][r]
  __shared__ float lds_g[16][33];

  for (int i = tid; i < TE * NB; i += 512) {
    int b = i & 31, s = i >> 5;
    int t = s;
    if (dir) { int L = lens[b]; t = (s < L) ? (L - 1 - s) : s; }
    tokL[i] = enc_in[b * TE + t];
  }
  if (tid < 128) {
    int b = tid >> 2, jj = tid & 3;
    stg1(&harr[((size_t)(dir * 129) * NB + b) * HH + ob * 4 + jj], 0.0f);
  }

  const int lane = tid & 63, w = tid >> 6;
  const int bq = lane >> 4, kl = lane & 15;
  const float* Wih = dir ? Wih_b : Wih_f;
  const float* Whh = dir ? Whh_b : Whh_f;
  const int r0 = 2 * w, r1 = 2 * w + 1;
  const int o0 = (r0 >> 2) * HH + ob * 4 + (r0 & 3);
  const int o1 = (r1 >> 2) * HH + ob * 4 + (r1 & 3);
  float4 W0[8], W1[8];
  #pragma unroll
  for (int c = 0; c < 8; ++c) {
    W0[c] = *(const float4*)&Whh[(size_t)o0 * HH + c * 64 + kl * 4];
    W1[c] = *(const float4*)&Whh[(size_t)o1 * HH + c * 64 + kl * 4];
  }

  // xpre role: thread = (xb batch, xr row); 16 lanes share one emb row (broadcast)
  const int xb = tid >> 4, xr = tid & 15;
  const int xo = (xr >> 2) * HH + ob * 4 + (xr & 3);
  const float4* xW4 = (const float4*)(Wih + (size_t)xo * EMB);
  const float bias_r = (dir ? bih_b : bih_f)[xo] + (dir ? bhh_b : bhh_f)[xo];

  // updater role (tid<128): (b_u, jj_u); c-state in register
  const int b_u = tid >> 2, jj_u = tid & 3;
  const int j_u = ob * 4 + jj_u;
  const int Lu = (tid < 128) ? lens[b_u] : 0;
  float cst = 0.0f;

  int tgt = 128;
  gbarM(cnt, tgt); tgt += 128;     // h0 + tokL visible

  for (int s = 0; s < TE; ++s) {
    if ((s & 15) == 0) {
      // precompute xpre for steps [s, s+16): dot(emb[tok], Wih_row) + bias
      for (int ss = 0; ss < 16; ++ss) {
        int tok = tokL[(s + ss) * 32 + xb];
        const float4* x4 = (const float4*)(emb_src + (size_t)tok * EMB);
        float4 a = {0,0,0,0}, b4 = {0,0,0,0};
        #pragma unroll 8
        for (int k = 0; k < 64; k += 2) {
          fma4(a,  xW4[k],     x4[k]);
          fma4(b4, xW4[k + 1], x4[k + 1]);
        }
        xpre[ss][xb][xr] = hsum4(a) + hsum4(b4) + bias_r;
      }
      __syncthreads();
    }

    const float* hbase = harr + ((size_t)(dir * 129 + s) * NB) * HH;
    // h @ Whh: two passes of 4 batch-groups; c-outer so all loads of a pass fly together
    #pragma unroll
    for (int half = 0; half < 2; ++half) {
      float4 a0[4] = {{0,0,0,0},{0,0,0,0},{0,0,0,0},{0,0,0,0}};
      float4 a1[4] = {{0,0,0,0},{0,0,0,0},{0,0,0,0},{0,0,0,0}};
      #pragma unroll
      for (int c = 0; c < 8; ++c) {
        #pragma unroll
        for (int bg = 0; bg < 4; ++bg) {
          int b = (half * 4 + bg) * 4 + bq;
          float4 u = *(const float4*)&hbase[(size_t)b * HH + c * 64 + kl * 4];
          fma4(a0[bg], W0[c], u);
          fma4(a1[bg], W1[c], u);
        }
      }
      #pragma unroll
      for (int bg = 0; bg < 4; ++bg) {
        int b = (half * 4 + bg) * 4 + bq;
        float s0 = hsum4(a0[bg]), s1 = hsum4(a1[bg]);
        s0 += __shfl_xor(s0, 1); s1 += __shfl_xor(s1, 1);
        s0 += __shfl_xor(s0, 2); s1 += __shfl_xor(s1, 2);
        s0 += __shfl_xor(s0, 4); s1 += __shfl_xor(s1, 4);
        s0 += __shfl_xor(s0, 8); s1 += __shfl_xor(s1, 8);
        if (kl == 0) { lds_g[r0][b] = s0; lds_g[r1][b] = s1; }
      }
    }
    __syncthreads();

    if (tid < 128) {
      const float* xp = &xpre[s & 15][b_u][0];
      float gi = xp[0  + jj_u] + lds_g[0  + jj_u][b_u];
      float gf = xp[4  + jj_u] + lds_g[4  + jj_u][b_u];
      float gg = xp[8  + jj_u] + lds_g[8  + jj_u][b_u];
      float go = xp[12 + jj_u] + lds_g[12 + jj_u][b_u];
      float c = sigf(gf) * cst + sigf(gi) * tanhf(gg);
      cst = c;
      float h = sigf(go) * tanhf(c);
      stg1(&harr[((size_t)(dir * 129 + s + 1) * NB + b_u) * HH + j_u], h);
      float hm = (s < Lu) ? h : 0.0f;
      int pos = dir ? ((s < Lu) ? (Lu - 1 - s) : s) : s;
      eo[((size_t)b_u * TE + pos) * CTXD + dir * HH + j_u] = hm;  // plain store
    }
    gbarM(cnt, tgt); tgt += 128;
  }
}

// ---------------- Decoder: 256 blocks x 512 thr, persistent ----------------
// P2: (pb=bid>>3, ds=bid&7) attn scores+softmax (redundant per ds) + 128-d ctx
// slice; TAIL of P2 = GRU x-part & h-part pre-dots (indep of ctx). P3: ctx-part
// dots (partials carried in regs across barrier) + update. 2 j-columns/block.
__global__ void __launch_bounds__(512)
dec_kernel(const int* __restrict__ dec_in, const int* __restrict__ lens,
           const float* __restrict__ emb_tgt,
           const float* __restrict__ gWih, const float* __restrict__ gWhh,
           const float* __restrict__ gbih, const float* __restrict__ gbhh,
           const float* __restrict__ attn_W, const float* __restrict__ attn_b,
           const float* __restrict__ attn_v,
           float* __restrict__ ws)
{
  const int tid = threadIdx.x, bid = blockIdx.x;
  int* cnt = (int*)ws + 128;
  float* eo   = ws + OEO;
  float* ep   = ws + OEP;
  float* dcat = ws + ODC;

  asm volatile("buffer_inv sc1" ::: "memory");

  __shared__ int tokD[TD * NB];
  __shared__ float av8[8];
  __shared__ float hpv[8];
  __shared__ float elds[128];
  __shared__ float wlds[128];
  __shared__ float redL[2];
  __shared__ float cpart[4][128];
  __shared__ float lds_d[2][6][33];

  for (int i = tid; i < TD * NB; i += 512) {
    int b = i & 31, s = i >> 5;
    tokD[i] = dec_in[b * TD + s];
  }
  if (tid < 8) av8[tid] = attn_v[tid];

  // pre-phase: ep = enc_out @ attn_W[:1024] + attn_b (blocks 0..63); h0 = 0
  {
    const int gt = bid * 512 + tid;
    if (gt < NB * TE * 8) {
      int a = gt & 7, t = (gt >> 3) & 127, b = gt >> 10;
      float acc = attn_b[a];
      const float* er = &eo[((size_t)b * TE + t) * CTXD];
      for (int d = 0; d < CTXD; d += 4) {
        float4 ev = *(const float4*)&er[d];
        acc = fmaf(ev.x, attn_W[(d + 0) * 8 + a], acc);
        acc = fmaf(ev.y, attn_W[(d + 1) * 8 + a], acc);
        acc = fmaf(ev.z, attn_W[(d + 2) * 8 + a], acc);
        acc = fmaf(ev.w, attn_W[(d + 3) * 8 + a], acc);
      }
      stg1(&ep[gt], acc);
    }
    int g2 = gt - NB * TE * 8;
    if (g2 >= 0 && g2 < NB * HH) {
      int b = g2 >> 9, j = g2 & 511;
      stg1(&dcat[(size_t)b * DCW + CTXD + j], 0.0f);
    }
  }

  const int pb = bid >> 3, ds = bid & 7;
  const int Lb = lens[pb];
  const int lane = tid & 63, w = tid >> 6;
  const int bq = lane >> 4, kl = lane & 15;

  // GRU weights in VGPRs: row = g*HH + 2*bid + jl, g = w>>1, jl = w&1
  float4 WD[28];
  if (w < 6) {
    const int row = (w >> 1) * HH + bid * 2 + (w & 1);
    #pragma unroll
    for (int c = 0; c < 28; ++c) {
      WD[c] = (c < 20) ? *(const float4*)&gWih[(size_t)row * (EMB + CTXD) + c * 64 + kl * 4]
                       : *(const float4*)&gWhh[(size_t)row * HH + (c - 20) * 64 + kl * 4];
    }
  }
  const int b_u = tid & 31, jl_u = tid >> 5;
  const int j_u = bid * 2 + jl_u;
  float bRi = 0, bRh = 0, bZi = 0, bZh = 0, bNi = 0, bNh = 0;
  if (tid < 64) {
    bRi = gbih[j_u];          bRh = gbhh[j_u];
    bZi = gbih[HH + j_u];     bZh = gbhh[HH + j_u];
    bNi = gbih[2 * HH + j_u]; bNh = gbhh[2 * HH + j_u];
  }
  float hreg = 0.0f;

  int tgt = 256;
  gbarM(cnt, tgt); tgt += 256;

  float4 iA[8];   // i-part partials (x-part now, ctx-part added in P3)

  for (int s = 0; s < TD; ++s) {
    // ---- P2: attn chain, ctx slice; tail = GRU pre-dots ----
    const float* hrow = dcat + ((size_t)s * NB + pb) * DCW + CTXD;
    {
      float acc = 0.0f;
      const float4* h4 = (const float4*)hrow;
      float4 ha = h4[lane * 2], hb = h4[lane * 2 + 1];
      const float* wa = attn_W + (size_t)(CTXD + lane * 8) * 8 + w;
      acc = fmaf(ha.x, wa[0],  acc); acc = fmaf(ha.y, wa[8],  acc);
      acc = fmaf(ha.z, wa[16], acc); acc = fmaf(ha.w, wa[24], acc);
      acc = fmaf(hb.x, wa[32], acc); acc = fmaf(hb.y, wa[40], acc);
      acc = fmaf(hb.z, wa[48], acc); acc = fmaf(hb.w, wa[56], acc);
      acc += __shfl_xor(acc, 1);  acc += __shfl_xor(acc, 2);
      acc += __shfl_xor(acc, 4);  acc += __shfl_xor(acc, 8);
      acc += __shfl_xor(acc, 16); acc += __shfl_xor(acc, 32);
      if (lane == 0) hpv[w] = acc;
    }
    __syncthreads();
    if (tid < 128) {
      float evv = -1e9f;
      if (tid < Lb) {
        const float* e8 = &ep[((size_t)pb * TE + tid) * 8];
        float4 ea = *(const float4*)e8, eb2 = *(const float4*)(e8 + 4);
        evv  = tanhf(ea.x + hpv[0]) * av8[0];
        evv += tanhf(ea.y + hpv[1]) * av8[1];
        evv += tanhf(ea.z + hpv[2]) * av8[2];
        evv += tanhf(ea.w + hpv[3]) * av8[3];
        evv += tanhf(eb2.x + hpv[4]) * av8[4];
        evv += tanhf(eb2.y + hpv[5]) * av8[5];
        evv += tanhf(eb2.z + hpv[6]) * av8[6];
        evv += tanhf(eb2.w + hpv[7]) * av8[7];
      }
      elds[tid] = evv;
    }
    __syncthreads();
    if (tid < 64) {
      float m = fmaxf(elds[tid], elds[tid + 64]);
      m = fmaxf(m, __shfl_xor(m, 1));  m = fmaxf(m, __shfl_xor(m, 2));
      m = fmaxf(m, __shfl_xor(m, 4));  m = fmaxf(m, __shfl_xor(m, 8));
      m = fmaxf(m, __shfl_xor(m, 16)); m = fmaxf(m, __shfl_xor(m, 32));
      if (tid == 0) redL[0] = m;
    }
    __syncthreads();
    float mx = redL[0];
    if (tid < 128) wlds[tid] = expf(elds[tid] - mx);
    __syncthreads();
    if (tid < 64) {
      float sm = wlds[tid] + wlds[tid + 64];
      sm += __shfl_xor(sm, 1);  sm += __shfl_xor(sm, 2);
      sm += __shfl_xor(sm, 4);  sm += __shfl_xor(sm, 8);
      sm += __shfl_xor(sm, 16); sm += __shfl_xor(sm, 32);
      if (tid == 0) redL[1] = 1.0f / sm;
    }
    {
      const int d = tid & 127, tq = tid >> 7;
      float acc = 0.0f;
      const float* eb = eo + ((size_t)pb * TE + tq * 32) * CTXD + ds * 128 + d;
      #pragma unroll 4
      for (int t = 0; t < 32; ++t)
        acc = fmaf(wlds[tq * 32 + t], eb[(size_t)t * CTXD], acc);
      cpart[tq][d] = acc;
    }
    __syncthreads();
    if (tid < 128) {
      float c = (cpart[0][tid] + cpart[1][tid] + cpart[2][tid] + cpart[3][tid]) * redL[1];
      stg1(&dcat[((size_t)s * NB + pb) * DCW + ds * 128 + tid], c);
    }
    // tail: GRU pre-dots (x-part c0..3, h-part c20..27) — indep of ctx
    if (w < 6) {
      #pragma unroll
      for (int bg = 0; bg < 8; ++bg) {
        int b = bg * 4 + bq;
        int tok = tokD[s * 32 + b];
        const float* xr_ = emb_tgt + (size_t)tok * EMB + kl * 4;
        const float* hr_ = dcat + ((size_t)s * NB + b) * DCW + CTXD + kl * 4;
        float4 ia = {0,0,0,0}, ha = {0,0,0,0}, hb2 = {0,0,0,0};
        #pragma unroll
        for (int c = 0; c < 4; ++c) fma4(ia, WD[c], *(const float4*)&xr_[c * 64]);
        #pragma unroll
        for (int c = 20; c < 28; ++c) {
          float4 u = *(const float4*)&hr_[(c - 20) * 64];
          if (c & 1) fma4(hb2, WD[c], u); else fma4(ha, WD[c], u);
        }
        iA[bg] = ia;
        float sh = hsum4(ha) + hsum4(hb2);
        sh += __shfl_xor(sh, 1); sh += __shfl_xor(sh, 2);
        sh += __shfl_xor(sh, 4); sh += __shfl_xor(sh, 8);
        if (kl == 0) lds_d[1][w][b] = sh;
      }
    }
    gbarM(cnt, tgt); tgt += 256;

    // ---- P3: ctx-part dots + update ----
    if (w < 6) {
      #pragma unroll
      for (int bg = 0; bg < 8; ++bg) {
        int b = bg * 4 + bq;
        const float* cr = dcat + ((size_t)s * NB + b) * DCW + kl * 4;
        float4 ia = iA[bg], ib = {0,0,0,0};
        #pragma unroll
        for (int c = 4; c < 20; ++c) {
          float4 u = *(const float4*)&cr[(c - 4) * 64];
          if (c & 1) fma4(ib, WD[c], u); else fma4(ia, WD[c], u);
        }
        float si = hsum4(ia) + hsum4(ib);
        si += __shfl_xor(si, 1); si += __shfl_xor(si, 2);
        si += __shfl_xor(si, 4); si += __shfl_xor(si, 8);
        if (kl == 0) lds_d[0][w][b] = si;
      }
    }
    __syncthreads();
    if (tid < 64) {
      float giR = lds_d[0][0 + jl_u][b_u], ghR = lds_d[1][0 + jl_u][b_u];
      float giZ = lds_d[0][2 + jl_u][b_u], ghZ = lds_d[1][2 + jl_u][b_u];
      float giN = lds_d[0][4 + jl_u][b_u], ghN = lds_d[1][4 + jl_u][b_u];
      float r = sigf(giR + bRi + ghR + bRh);
      float z = sigf(giZ + bZi + ghZ + bZh);
      float n = tanhf(giN + bNi + r * (ghN + bNh));
      float hnew = (1.0f - z) * n + z * hreg;
      hreg = hnew;
      stg1(&dcat[((size_t)(s + 1) * NB + b_u) * DCW + CTXD + j_u], hnew);
    }
    gbarM(cnt, tgt); tgt += 256;
  }
}

// ---------------- Classifier: [1024,512] @ clf_W^T [512,32000], relu ----------------
__global__ void __launch_bounds__(256)
clf_kernel(const float* __restrict__ dcat, const float* __restrict__ W,
           const float* __restrict__ bias, float* __restrict__ out)
{
  asm volatile("buffer_inv sc1" ::: "memory");  // stale-clean-line insurance (replays)
  __shared__ __align__(16) float As[16][68];
  __shared__ __align__(16) float Bs[16][68];
  const int tid = threadIdx.x;
  const int tx = tid & 15, ty = tid >> 4;
  const int n0 = blockIdx.x * 64, m0 = blockIdx.y * 64;
  float acc[4][4] = {};
  const int lr = tid >> 2;
  const int lk = (tid & 3) * 4;
  const int r  = m0 + lr;                       // r = b*TD + t
  const float* arow = dcat + ((size_t)((r & 31) + 1) * NB + (r >> 5)) * DCW + CTXD;
  const float* brow = W + (size_t)(n0 + lr) * HH;

  for (int kc = 0; kc < HH; kc += 16) {
    float4 av = *(const float4*)&arow[kc + lk];
    float4 bv = *(const float4*)&brow[kc + lk];
    __syncthreads();
    As[lk + 0][lr] = av.x; As[lk + 1][lr] = av.y;
    As[lk + 2][lr] = av.z; As[lk + 3][lr] = av.w;
    Bs[lk + 0][lr] = bv.x; Bs[lk + 1][lr] = bv.y;
    Bs[lk + 2][lr] = bv.z; Bs[lk + 3][lr] = bv.w;
    __syncthreads();
    #pragma unroll
    for (int kk = 0; kk < 16; ++kk) {
      float4 a4 = *(const float4*)&As[kk][ty * 4];
      float4 b4 = *(const float4*)&Bs[kk][tx * 4];
      acc[0][0] = fmaf(a4.x, b4.x, acc[0][0]); acc[0][1] = fmaf(a4.x, b4.y, acc[0][1]);
      acc[0][2] = fmaf(a4.x, b4.z, acc[0][2]); acc[0][3] = fmaf(a4.x, b4.w, acc[0][3]);
      acc[1][0] = fmaf(a4.y, b4.x, acc[1][0]); acc[1][1] = fmaf(a4.y, b4.y, acc[1][1]);
      acc[1][2] = fmaf(a4.y, b4.z, acc[1][2]); acc[1][3] = fmaf(a4.y, b4.w, acc[1][3]);
      acc[2][0] = fmaf(a4.z, b4.x, acc[2][0]); acc[2][1] = fmaf(a4.z, b4.y, acc[2][1]);
      acc[2][2] = fmaf(a4.z, b4.z, acc[2][2]); acc[2][3] = fmaf(a4.z, b4.w, acc[2][3]);
      acc[3][0] = fmaf(a4.w, b4.x, acc[3][0]); acc[3][1] = fmaf(a4.w, b4.y, acc[3][1]);
      acc[3][2] = fmaf(a4.w, b4.z, acc[3][2]); acc[3][3] = fmaf(a4.w, b4.w, acc[3][3]);
    }
  }
  const int col = n0 + tx * 4;
  float4 bb4 = *(const float4*)&bias[col];
  #pragma unroll
  for (int i = 0; i < 4; ++i) {
    int row = m0 + ty * 4 + i;
    float4 o;
    o.x = fmaxf(acc[i][0] + bb4.x, 0.0f);
    o.y = fmaxf(acc[i][1] + bb4.y, 0.0f);
    o.z = fmaxf(acc[i][2] + bb4.z, 0.0f);
    o.w = fmaxf(acc[i][3] + bb4.w, 0.0f);
    *(float4*)&out[(size_t)row * VOC + col] = o;
  }
}

extern "C" void kernel_launch(void* const* d_in, const int* in_sizes, int n_in,
                              void* d_out, int out_size, void* d_ws, size_t ws_size,
                              hipStream_t stream)
{
  if (ws_size < (size_t)WSEND * 4) return;  // visible-failure guard

  const int* enc_in  = (const int*)d_in[0];
  const int* enc_len = (const int*)d_in[1];
  const int* dec_in  = (const int*)d_in[2];
  const float* emb_src = (const float*)d_in[4];
  const float* emb_tgt = (const float*)d_in[5];
  const float* Wih_f = (const float*)d_in[6];
  const float* Whh_f = (const float*)d_in[7];
  const float* bih_f = (const float*)d_in[8];
  const float* bhh_f = (const float*)d_in[9];
  const float* Wih_b = (const float*)d_in[10];
  const float* Whh_b = (const float*)d_in[11];
  const float* bih_b = (const float*)d_in[12];
  const float* bhh_b = (const float*)d_in[13];
  const float* gWih  = (const float*)d_in[14];
  const float* gWhh  = (const float*)d_in[15];
  const float* gbih  = (const float*)d_in[16];
  const float* gbhh  = (const float*)d_in[17];
  const float* attn_W = (const float*)d_in[18];
  const float* attn_b = (const float*)d_in[19];
  const float* attn_v = (const float*)d_in[20];
  const float* clf_W = (const float*)d_in[21];
  const float* clf_b = (const float*)d_in[22];
  float* ws  = (float*)d_ws;
  float* out = (float*)d_out;

  hipMemsetAsync(d_ws, 0, 4096, stream);  // monotonic counters
  scan_kernel<<<256, 512, 0, stream>>>(enc_in, enc_len, emb_src,
      Wih_f, Whh_f, bih_f, bhh_f, Wih_b, Whh_b, bih_b, bhh_b, ws);
  dec_kernel<<<256, 512, 0, stream>>>(dec_in, enc_len, emb_tgt,
      gWih, gWhh, gbih, gbhh, attn_W, attn_b, attn_v, ws);
  dim3 cg(VOC / 64, (NB * TD) / 64);
  clf_kernel<<<cg, 256, 0, stream>>>(ws + ODC, clf_W, clf_b, out);
}